// Round 1
// baseline (17781.746 us; speedup 1.0000x reference)
//
#include <hip/hip_runtime.h>
#include <hip/hip_bf16.h>

#define N_NODES   100000
#define N_EDGES   1600000
#define CH        128
#define N_GRAPHS  512
#define N_CLASSES 64
#define BN_EPS    1e-5f

typedef unsigned int uint;
typedef unsigned short ushort_t;

__device__ __forceinline__ ushort_t f2bf(float f) {
    uint u = __float_as_uint(f);
    uint r = (u + 0x7fffu + ((u >> 16) & 1u)) >> 16;   // round-to-nearest-even
    return (ushort_t)r;
}
__device__ __forceinline__ float bf2f(ushort_t u) {
    return __uint_as_float(((uint)u) << 16);
}

// ---------------- degree / dinv ----------------
__global__ __launch_bounds__(256) void k_deg(const int* __restrict__ dst, float* __restrict__ deg) {
    int e = blockIdx.x * 256 + threadIdx.x;
    if (e < N_EDGES) atomicAdd(&deg[dst[e]], 1.0f);
}

__global__ __launch_bounds__(256) void k_dinv(float* __restrict__ deg) {
    int i = blockIdx.x * 256 + threadIdx.x;
    if (i < N_NODES) deg[i] = rsqrtf(deg[i] + 1.0f);
}

// ---------------- GEMM: H(bf16) = X(fp32) @ W(fp32) ----------------
// block: 256 threads, tile 64 rows x 128 cols, K chunked by 64. LDS 48 KB.
__global__ __launch_bounds__(256) void k_gemm(const float* __restrict__ X,
                                              const float* __restrict__ W,
                                              ushort_t* __restrict__ H) {
    __shared__ float sW[64 * 128];   // [k][c] chunk
    __shared__ float sX[64 * 64];    // [r][k] chunk
    const int t = threadIdx.x;
    const int row0 = blockIdx.x * 64;
    const int cg = t & 31;   // col group: cols cg*4 .. cg*4+3
    const int rg = t >> 5;   // row group: rows rg*8 .. rg*8+7

    float acc[8][4];
#pragma unroll
    for (int j = 0; j < 8; ++j) { acc[j][0]=0.f; acc[j][1]=0.f; acc[j][2]=0.f; acc[j][3]=0.f; }

    for (int kc = 0; kc < 128; kc += 64) {
        // load W chunk: 64x128 floats
        for (int i = t; i < 2048; i += 256) {
            int off = i * 4;
            int kk = off >> 7;          // 0..63
            int cc = off & 127;
            *(float4*)&sW[off] = *(const float4*)&W[(kc + kk) * 128 + cc];
        }
        // load X tile: 64 rows x 64 k
        for (int i = t; i < 1024; i += 256) {
            int off = i * 4;
            int r = off >> 6;           // 0..63
            int kk = off & 63;
            float4 v = make_float4(0.f, 0.f, 0.f, 0.f);
            int gr = row0 + r;
            if (gr < N_NODES) v = *(const float4*)&X[gr * 128 + kc + kk];
            *(float4*)&sX[off] = v;
        }
        __syncthreads();

        for (int k = 0; k < 64; ++k) {
            float4 w = *(float4*)&sW[k * 128 + cg * 4];
#pragma unroll
            for (int j = 0; j < 8; ++j) {
                float xv = sX[(rg * 8 + j) * 64 + k];
                acc[j][0] += xv * w.x;
                acc[j][1] += xv * w.y;
                acc[j][2] += xv * w.z;
                acc[j][3] += xv * w.w;
            }
        }
        __syncthreads();
    }

#pragma unroll
    for (int j = 0; j < 8; ++j) {
        int r = row0 + rg * 8 + j;
        if (r < N_NODES) {
            ushort4 o;
            o.x = f2bf(acc[j][0]); o.y = f2bf(acc[j][1]);
            o.z = f2bf(acc[j][2]); o.w = f2bf(acc[j][3]);
            *(ushort4*)(H + r * 128 + cg * 4) = o;
        }
    }
}

// ---------------- agg init: AGG = h*dinv^2 + b ----------------
__global__ __launch_bounds__(256) void k_agg_init(const ushort_t* __restrict__ H,
                                                  const float* __restrict__ dinv,
                                                  const float* __restrict__ b,
                                                  float* __restrict__ AGG) {
    int tid = blockIdx.x * 256 + threadIdx.x;    // N*16 threads, 8 ch each
    if (tid >= N_NODES * 16) return;
    int i = tid >> 4;
    int g = tid & 15;
    float d = dinv[i];
    float d2 = d * d;
    union { uint4 v; ushort_t u[8]; } hu;
    hu.v = *(const uint4*)(H + i * 128 + g * 8);
    float* ap = AGG + i * 128 + g * 8;
    const float* bp = b + g * 8;
#pragma unroll
    for (int j = 0; j < 8; ++j) {
        ap[j] = bf2f(hu.u[j]) * d2 + bp[j];
    }
}

// ---------------- edge scatter: AGG[dst] += dinv[src]*dinv[dst]*h[src] ----------------
__global__ __launch_bounds__(256) void k_scatter(const int* __restrict__ src,
                                                 const int* __restrict__ dst,
                                                 const float* __restrict__ dinv,
                                                 const ushort_t* __restrict__ H,
                                                 float* __restrict__ AGG) {
    int tid = blockIdx.x * 256 + threadIdx.x;    // E*16 threads, 8 ch each
    if (tid >= N_EDGES * 16) return;
    int e = tid >> 4;
    int g = tid & 15;
    int s = src[e];
    int d = dst[e];
    float coef = dinv[s] * dinv[d];
    union { uint4 v; ushort_t u[8]; } hu;
    hu.v = *(const uint4*)(H + s * 128 + g * 8);
    float* ap = AGG + d * 128 + g * 8;
#pragma unroll
    for (int j = 0; j < 8; ++j) {
        atomicAdd(ap + j, coef * bf2f(hu.u[j]));
    }
}

// ---------------- BN stats: per-channel sum / sumsq ----------------
__global__ __launch_bounds__(128) void k_bn_stats(const float* __restrict__ AGG,
                                                  float* __restrict__ stats) {
    int c = threadIdx.x;
    float s = 0.f, q = 0.f;
    for (int i = blockIdx.x; i < N_NODES; i += gridDim.x) {
        float v = AGG[i * 128 + c];
        s += v;
        q += v * v;
    }
    atomicAdd(&stats[c], s);
    atomicAdd(&stats[128 + c], q);
}

__global__ __launch_bounds__(128) void k_bn_finalize(float* __restrict__ stats,
                                                     const float* __restrict__ gamma,
                                                     const float* __restrict__ beta) {
    int c = threadIdx.x;
    const float invN = 1.0f / (float)N_NODES;
    float mu = stats[c] * invN;
    float var = stats[128 + c] * invN - mu * mu;
    float sc = gamma[c] * rsqrtf(var + BN_EPS);
    stats[256 + c] = sc;
    stats[384 + c] = beta[c] - mu * sc;
}

// ---------------- BN apply + ReLU (+ residual) ----------------
__global__ __launch_bounds__(256) void k_bn_apply(const float* __restrict__ AGG,
                                                  const float* __restrict__ stats,
                                                  const float* __restrict__ RES,  // may be null
                                                  float* __restrict__ OUT) {
    int tid = blockIdx.x * 256 + threadIdx.x;    // N*32 threads, 4 ch each
    if (tid >= N_NODES * 32) return;
    int i = tid >> 5;
    int c = (tid & 31) * 4;
    float4 v = *(const float4*)&AGG[i * 128 + c];
    float4 sc = *(const float4*)&stats[256 + c];
    float4 sh = *(const float4*)&stats[384 + c];
    float4 y;
    y.x = v.x * sc.x + sh.x;
    y.y = v.y * sc.y + sh.y;
    y.z = v.z * sc.z + sh.z;
    y.w = v.w * sc.w + sh.w;
    if (RES) {
        float4 r = *(const float4*)&RES[i * 128 + c];
        y.x += r.x; y.y += r.y; y.z += r.z; y.w += r.w;
    }
    y.x = fmaxf(y.x, 0.f); y.y = fmaxf(y.y, 0.f);
    y.z = fmaxf(y.z, 0.f); y.w = fmaxf(y.w, 0.f);
    *(float4*)&OUT[i * 128 + c] = y;
}

// ---------------- pooling ----------------
__global__ __launch_bounds__(256) void k_pool(const float* __restrict__ X,
                                              const int* __restrict__ batch,
                                              float* __restrict__ psum,
                                              uint* __restrict__ pmax,
                                              float* __restrict__ pcnt) {
    int tid = blockIdx.x * 256 + threadIdx.x;    // N*32 threads, 4 ch each
    if (tid >= N_NODES * 32) return;
    int i = tid >> 5;
    int g = tid & 31;
    int c = g * 4;
    int b = batch[i];
    float4 v = *(const float4*)&X[i * 128 + c];
    float* sp = psum + b * 128 + c;
    uint* mp = pmax + b * 128 + c;
    atomicAdd(sp + 0, v.x);
    atomicAdd(sp + 1, v.y);
    atomicAdd(sp + 2, v.z);
    atomicAdd(sp + 3, v.w);
    // post-ReLU values are >= 0, so uint compare == float compare; init 0 handles empty graphs
    atomicMax(mp + 0, __float_as_uint(v.x));
    atomicMax(mp + 1, __float_as_uint(v.y));
    atomicMax(mp + 2, __float_as_uint(v.z));
    atomicMax(mp + 3, __float_as_uint(v.w));
    if (g == 0) atomicAdd(&pcnt[b], 1.0f);
}

// ---------------- head: out[g][o] = pooled[g] . Wh[:,o] + bh[o] ----------------
__global__ __launch_bounds__(64) void k_head(const float* __restrict__ psum,
                                             const uint* __restrict__ pmax,
                                             const float* __restrict__ pcnt,
                                             const float* __restrict__ Wh,
                                             const float* __restrict__ bh,
                                             float* __restrict__ out) {
    int g = blockIdx.x;
    int o = threadIdx.x;
    float cnt = pcnt[g];
    float inv = 1.0f / fmaxf(cnt, 1.0f);
    float acc = bh[o];
    for (int c = 0; c < 128; ++c) {
        float s = psum[g * 128 + c];
        float m = __uint_as_float(pmax[g * 128 + c]);
        acc += (s * inv) * Wh[c * 64 + o];
        acc += s * Wh[(128 + c) * 64 + o];
        acc += m * Wh[(256 + c) * 64 + o];
    }
    out[g * 64 + o] = acc;
}

// ---------------- host orchestration ----------------
extern "C" void kernel_launch(void* const* d_in, const int* in_sizes, int n_in,
                              void* d_out, int out_size, void* d_ws, size_t ws_size,
                              hipStream_t stream) {
    const float* x     = (const float*)d_in[0];
    const int*   ei    = (const int*)d_in[1];
    const int*   batch = (const int*)d_in[2];
    const float* W1 = (const float*)d_in[3];
    const float* b1 = (const float*)d_in[4];
    const float* g1 = (const float*)d_in[5];
    const float* be1= (const float*)d_in[6];
    const float* W2 = (const float*)d_in[7];
    const float* b2 = (const float*)d_in[8];
    const float* g2 = (const float*)d_in[9];
    const float* be2= (const float*)d_in[10];
    const float* W3 = (const float*)d_in[11];
    const float* b3 = (const float*)d_in[12];
    const float* g3 = (const float*)d_in[13];
    const float* be3= (const float*)d_in[14];
    const float* Wh = (const float*)d_in[15];
    const float* bh = (const float*)d_in[16];

    const int* src = ei;
    const int* dst = ei + N_EDGES;

    char* ws = (char*)d_ws;
    size_t off = 0;
    float* dinv = (float*)(ws + off);             off += 512 * 1024;                  // 400 KB used
    float* bufA = (float*)(ws + off);             off += (size_t)N_NODES * CH * 4;    // 51.2 MB
    float* bufB = (float*)(ws + off);             off += (size_t)N_NODES * CH * 4;    // 51.2 MB
    ushort_t* H = (ushort_t*)(ws + off);          off += (size_t)N_NODES * CH * 2;    // 25.6 MB
    float* AGG  = (float*)(ws + off);             off += (size_t)N_NODES * CH * 4;    // 51.2 MB
    float* stats= (float*)(ws + off);             off += 512 * 4;                     // 2 KB
    float* psum = (float*)(ws + off);             off += (size_t)N_GRAPHS * CH * 4;
    uint*  pmax = (uint*)(ws + off);              off += (size_t)N_GRAPHS * CH * 4;
    float* pcnt = (float*)(ws + off);             off += (size_t)N_GRAPHS * 4;

    // degree -> dinv (in place)
    hipMemsetAsync(dinv, 0, N_NODES * 4, stream);
    k_deg<<<(N_EDGES + 255) / 256, 256, 0, stream>>>(dst, dinv);
    k_dinv<<<(N_NODES + 255) / 256, 256, 0, stream>>>(dinv);

    const int gemm_grid  = (N_NODES + 63) / 64;
    const int init_grid  = (N_NODES * 16 + 255) / 256;
    const int scat_grid  = (N_EDGES * 16 + 255) / 256;
    const int apply_grid = (N_NODES * 32 + 255) / 256;

    struct Layer { const float* in; float* out; const float* W; const float* b;
                   const float* gm; const float* bt; const float* res; };
    Layer layers[3] = {
        { x,    bufA, W1, b1, g1, be1, nullptr },
        { bufA, bufB, W2, b2, g2, be2, bufA    },
        { bufB, bufA, W3, b3, g3, be3, bufB    },
    };

    for (int l = 0; l < 3; ++l) {
        const Layer& L = layers[l];
        k_gemm<<<gemm_grid, 256, 0, stream>>>(L.in, L.W, H);
        k_agg_init<<<init_grid, 256, 0, stream>>>(H, dinv, L.b, AGG);
        k_scatter<<<scat_grid, 256, 0, stream>>>(src, dst, dinv, H, AGG);
        hipMemsetAsync(stats, 0, 2 * CH * 4, stream);
        k_bn_stats<<<1024, 128, 0, stream>>>(AGG, stats);
        k_bn_finalize<<<1, 128, 0, stream>>>(stats, L.gm, L.bt);
        k_bn_apply<<<apply_grid, 256, 0, stream>>>(AGG, stats, L.res, L.out);
    }

    // pooling (layer-3 output is in bufA)
    hipMemsetAsync(psum, 0, (size_t)N_GRAPHS * CH * 4, stream);
    hipMemsetAsync(pmax, 0, (size_t)N_GRAPHS * CH * 4, stream);
    hipMemsetAsync(pcnt, 0, (size_t)N_GRAPHS * 4, stream);
    k_pool<<<apply_grid, 256, 0, stream>>>(bufA, batch, psum, pmax, pcnt);
    k_head<<<N_GRAPHS, 64, 0, stream>>>(psum, pmax, pcnt, Wh, bh, (float*)d_out);
}

// Round 2
// 1469.986 us; speedup vs baseline: 12.0965x; 12.0965x over previous
//
#include <hip/hip_runtime.h>
#include <hip/hip_bf16.h>

#define N_NODES   100000
#define N_EDGES   1600000
#define CH        128
#define N_GRAPHS  512
#define N_CLASSES 64
#define BN_EPS    1e-5f

typedef unsigned int uint;
typedef unsigned short ushort_t;

__device__ __forceinline__ ushort_t f2bf(float f) {
    uint u = __float_as_uint(f);
    uint r = (u + 0x7fffu + ((u >> 16) & 1u)) >> 16;   // round-to-nearest-even
    return (ushort_t)r;
}
__device__ __forceinline__ float bf2f(ushort_t u) {
    return __uint_as_float(((uint)u) << 16);
}

// ---------------- degree count (int) ----------------
__global__ __launch_bounds__(256) void k_deg(const int* __restrict__ dst, int* __restrict__ cnt) {
    int e = blockIdx.x * 256 + threadIdx.x;
    if (e < N_EDGES) atomicAdd(&cnt[dst[e]], 1);
}

__global__ __launch_bounds__(256) void k_dinv(const int* __restrict__ cnt, float* __restrict__ dinv) {
    int i = blockIdx.x * 256 + threadIdx.x;
    if (i < N_NODES) dinv[i] = rsqrtf((float)cnt[i] + 1.0f);
}

// ---------------- exclusive scan (3-kernel, 100K elems) ----------------
// pass 1: per-block (512 elems) exclusive scan + block total
__global__ __launch_bounds__(512) void k_scan1(const int* __restrict__ cnt,
                                               int* __restrict__ lofs,
                                               int* __restrict__ bsum) {
    __shared__ int sd[512];
    int t = threadIdx.x;
    int i = blockIdx.x * 512 + t;
    int v = (i < N_NODES) ? cnt[i] : 0;
    sd[t] = v;
    __syncthreads();
    for (int o = 1; o < 512; o <<= 1) {
        int x = (t >= o) ? sd[t - o] : 0;
        __syncthreads();
        sd[t] += x;
        __syncthreads();
    }
    if (i < N_NODES) lofs[i] = sd[t] - v;     // exclusive
    if (t == 511) bsum[blockIdx.x] = sd[511];
}

// pass 2: scan block sums (196 of them) — single thread, trivial
__global__ __launch_bounds__(64) void k_scan2(int* __restrict__ bsum, int nblocks) {
    if (threadIdx.x == 0 && blockIdx.x == 0) {
        int run = 0;
        for (int b = 0; b < nblocks; ++b) {
            int v = bsum[b];
            bsum[b] = run;
            run += v;
        }
    }
}

// pass 3: add block offsets -> final offs; set offs[N] = E
__global__ __launch_bounds__(256) void k_scan3(const int* __restrict__ lofs,
                                               const int* __restrict__ bsum,
                                               int* __restrict__ offs) {
    int i = blockIdx.x * 256 + threadIdx.x;
    if (i < N_NODES) offs[i] = lofs[i] + bsum[i >> 9];
    if (i == 0) offs[N_NODES] = N_EDGES;
}

// ---------------- CSR fill: csr_src[pos] = src[e], bucketed by dst ----------------
__global__ __launch_bounds__(256) void k_fill(const int* __restrict__ src,
                                              const int* __restrict__ dst,
                                              const int* __restrict__ offs,
                                              int* __restrict__ cursor,
                                              int* __restrict__ csr_src) {
    int e = blockIdx.x * 256 + threadIdx.x;
    if (e >= N_EDGES) return;
    int d = dst[e];
    int pos = offs[d] + atomicAdd(&cursor[d], 1);
    csr_src[pos] = src[e];
}

// ---------------- GEMM: H(bf16) = X(fp32) @ W(fp32) ----------------
__global__ __launch_bounds__(256) void k_gemm(const float* __restrict__ X,
                                              const float* __restrict__ W,
                                              ushort_t* __restrict__ H) {
    __shared__ float sW[64 * 128];   // [k][c] chunk
    __shared__ float sX[64 * 64];    // [r][k] chunk
    const int t = threadIdx.x;
    const int row0 = blockIdx.x * 64;
    const int cg = t & 31;   // col group: cols cg*4 .. cg*4+3
    const int rg = t >> 5;   // row group: rows rg*8 .. rg*8+7

    float acc[8][4];
#pragma unroll
    for (int j = 0; j < 8; ++j) { acc[j][0]=0.f; acc[j][1]=0.f; acc[j][2]=0.f; acc[j][3]=0.f; }

    for (int kc = 0; kc < 128; kc += 64) {
        for (int i = t; i < 2048; i += 256) {
            int off = i * 4;
            int kk = off >> 7;
            int cc = off & 127;
            *(float4*)&sW[off] = *(const float4*)&W[(kc + kk) * 128 + cc];
        }
        for (int i = t; i < 1024; i += 256) {
            int off = i * 4;
            int r = off >> 6;
            int kk = off & 63;
            float4 v = make_float4(0.f, 0.f, 0.f, 0.f);
            int gr = row0 + r;
            if (gr < N_NODES) v = *(const float4*)&X[gr * 128 + kc + kk];
            *(float4*)&sX[off] = v;
        }
        __syncthreads();

        for (int k = 0; k < 64; ++k) {
            float4 w = *(float4*)&sW[k * 128 + cg * 4];
#pragma unroll
            for (int j = 0; j < 8; ++j) {
                float xv = sX[(rg * 8 + j) * 64 + k];
                acc[j][0] += xv * w.x;
                acc[j][1] += xv * w.y;
                acc[j][2] += xv * w.z;
                acc[j][3] += xv * w.w;
            }
        }
        __syncthreads();
    }

#pragma unroll
    for (int j = 0; j < 8; ++j) {
        int r = row0 + rg * 8 + j;
        if (r < N_NODES) {
            ushort4 o;
            o.x = f2bf(acc[j][0]); o.y = f2bf(acc[j][1]);
            o.z = f2bf(acc[j][2]); o.w = f2bf(acc[j][3]);
            *(ushort4*)(H + r * 128 + cg * 4) = o;
        }
    }
}

// ---------------- gather-aggregate: one wave per dst node ----------------
// AGG[i] = sum_{src in csr[i]} dinv[src]*dinv[i]*h[src] + dinv[i]^2*h[i] + b
__global__ __launch_bounds__(256) void k_gather(const int* __restrict__ csr_src,
                                                const int* __restrict__ offs,
                                                const float* __restrict__ dinv,
                                                const ushort_t* __restrict__ H,
                                                const float* __restrict__ b,
                                                float* __restrict__ AGG) {
    int node = blockIdx.x * 4 + (threadIdx.x >> 6);
    if (node >= N_NODES) return;
    int lane = threadIdx.x & 63;
    int c = lane * 2;

    float di = dinv[node];
    float d2 = di * di;
    uint hv = *(const uint*)(H + (size_t)node * 128 + c);
    float acc0 = bf2f((ushort_t)(hv & 0xffff)) * d2 + b[c];
    float acc1 = bf2f((ushort_t)(hv >> 16))    * d2 + b[c + 1];

    int beg = offs[node];
    int end = offs[node + 1];
    int s_next = (beg < end) ? csr_src[beg] : 0;
    for (int p = beg; p < end; ++p) {
        int s = s_next;
        if (p + 1 < end) s_next = csr_src[p + 1];
        float coef = dinv[s] * di;
        uint h = *(const uint*)(H + (size_t)s * 128 + c);
        acc0 += coef * bf2f((ushort_t)(h & 0xffff));
        acc1 += coef * bf2f((ushort_t)(h >> 16));
    }

    *(float2*)(AGG + (size_t)node * 128 + c) = make_float2(acc0, acc1);
}

// ---------------- BN stats: per-channel sum / sumsq ----------------
__global__ __launch_bounds__(128) void k_bn_stats(const float* __restrict__ AGG,
                                                  float* __restrict__ stats) {
    int c = threadIdx.x;
    float s = 0.f, q = 0.f;
    for (int i = blockIdx.x; i < N_NODES; i += gridDim.x) {
        float v = AGG[i * 128 + c];
        s += v;
        q += v * v;
    }
    atomicAdd(&stats[c], s);
    atomicAdd(&stats[128 + c], q);
}

__global__ __launch_bounds__(128) void k_bn_finalize(float* __restrict__ stats,
                                                     const float* __restrict__ gamma,
                                                     const float* __restrict__ beta) {
    int c = threadIdx.x;
    const float invN = 1.0f / (float)N_NODES;
    float mu = stats[c] * invN;
    float var = stats[128 + c] * invN - mu * mu;
    float sc = gamma[c] * rsqrtf(var + BN_EPS);
    stats[256 + c] = sc;
    stats[384 + c] = beta[c] - mu * sc;
}

// ---------------- BN apply + ReLU (+ residual) ----------------
__global__ __launch_bounds__(256) void k_bn_apply(const float* __restrict__ AGG,
                                                  const float* __restrict__ stats,
                                                  const float* __restrict__ RES,  // may be null
                                                  float* __restrict__ OUT) {
    int tid = blockIdx.x * 256 + threadIdx.x;
    if (tid >= N_NODES * 32) return;
    int i = tid >> 5;
    int c = (tid & 31) * 4;
    float4 v = *(const float4*)&AGG[i * 128 + c];
    float4 sc = *(const float4*)&stats[256 + c];
    float4 sh = *(const float4*)&stats[384 + c];
    float4 y;
    y.x = v.x * sc.x + sh.x;
    y.y = v.y * sc.y + sh.y;
    y.z = v.z * sc.z + sh.z;
    y.w = v.w * sc.w + sh.w;
    if (RES) {
        float4 r = *(const float4*)&RES[i * 128 + c];
        y.x += r.x; y.y += r.y; y.z += r.z; y.w += r.w;
    }
    y.x = fmaxf(y.x, 0.f); y.y = fmaxf(y.y, 0.f);
    y.z = fmaxf(y.z, 0.f); y.w = fmaxf(y.w, 0.f);
    *(float4*)&OUT[i * 128 + c] = y;
}

// ---------------- pooling ----------------
__global__ __launch_bounds__(256) void k_pool(const float* __restrict__ X,
                                              const int* __restrict__ batch,
                                              float* __restrict__ psum,
                                              uint* __restrict__ pmax,
                                              float* __restrict__ pcnt) {
    int tid = blockIdx.x * 256 + threadIdx.x;
    if (tid >= N_NODES * 32) return;
    int i = tid >> 5;
    int g = tid & 31;
    int c = g * 4;
    int b = batch[i];
    float4 v = *(const float4*)&X[i * 128 + c];
    float* sp = psum + b * 128 + c;
    uint* mp = pmax + b * 128 + c;
    atomicAdd(sp + 0, v.x);
    atomicAdd(sp + 1, v.y);
    atomicAdd(sp + 2, v.z);
    atomicAdd(sp + 3, v.w);
    atomicMax(mp + 0, __float_as_uint(v.x));
    atomicMax(mp + 1, __float_as_uint(v.y));
    atomicMax(mp + 2, __float_as_uint(v.z));
    atomicMax(mp + 3, __float_as_uint(v.w));
    if (g == 0) atomicAdd(&pcnt[b], 1.0f);
}

// ---------------- head ----------------
__global__ __launch_bounds__(64) void k_head(const float* __restrict__ psum,
                                             const uint* __restrict__ pmax,
                                             const float* __restrict__ pcnt,
                                             const float* __restrict__ Wh,
                                             const float* __restrict__ bh,
                                             float* __restrict__ out) {
    int g = blockIdx.x;
    int o = threadIdx.x;
    float cnt = pcnt[g];
    float inv = 1.0f / fmaxf(cnt, 1.0f);
    float acc = bh[o];
    for (int c = 0; c < 128; ++c) {
        float s = psum[g * 128 + c];
        float m = __uint_as_float(pmax[g * 128 + c]);
        acc += (s * inv) * Wh[c * 64 + o];
        acc += s * Wh[(128 + c) * 64 + o];
        acc += m * Wh[(256 + c) * 64 + o];
    }
    out[g * 64 + o] = acc;
}

// ---------------- host orchestration ----------------
extern "C" void kernel_launch(void* const* d_in, const int* in_sizes, int n_in,
                              void* d_out, int out_size, void* d_ws, size_t ws_size,
                              hipStream_t stream) {
    const float* x     = (const float*)d_in[0];
    const int*   ei    = (const int*)d_in[1];
    const int*   batch = (const int*)d_in[2];
    const float* W1 = (const float*)d_in[3];
    const float* b1 = (const float*)d_in[4];
    const float* g1 = (const float*)d_in[5];
    const float* be1= (const float*)d_in[6];
    const float* W2 = (const float*)d_in[7];
    const float* b2 = (const float*)d_in[8];
    const float* g2 = (const float*)d_in[9];
    const float* be2= (const float*)d_in[10];
    const float* W3 = (const float*)d_in[11];
    const float* b3 = (const float*)d_in[12];
    const float* g3 = (const float*)d_in[13];
    const float* be3= (const float*)d_in[14];
    const float* Wh = (const float*)d_in[15];
    const float* bh = (const float*)d_in[16];

    const int* src = ei;
    const int* dst = ei + N_EDGES;

    char* ws = (char*)d_ws;
    size_t off = 0;
    float* dinv   = (float*)(ws + off);   off += 512 * 1024;
    float* bufA   = (float*)(ws + off);   off += (size_t)N_NODES * CH * 4;
    float* bufB   = (float*)(ws + off);   off += (size_t)N_NODES * CH * 4;
    ushort_t* H   = (ushort_t*)(ws + off);off += (size_t)N_NODES * CH * 2;
    float* AGG    = (float*)(ws + off);   off += (size_t)N_NODES * CH * 4;
    float* stats  = (float*)(ws + off);   off += 512 * 4;
    float* psum   = (float*)(ws + off);   off += (size_t)N_GRAPHS * CH * 4;
    uint*  pmax   = (uint*)(ws + off);    off += (size_t)N_GRAPHS * CH * 4;
    float* pcnt   = (float*)(ws + off);   off += 4096;
    int*   cnt    = (int*)(ws + off);     off += 512 * 1024;
    int*   lofs   = (int*)(ws + off);     off += 512 * 1024;
    int*   offs   = (int*)(ws + off);     off += 512 * 1024;      // N+1 ints
    int*   bsum   = (int*)(ws + off);     off += 4096;
    int*   cursor = (int*)(ws + off);     off += 512 * 1024;
    int*   csr_src= (int*)(ws + off);     off += (size_t)N_EDGES * 4;

    const int SCAN_BLOCKS = (N_NODES + 511) / 512;   // 196

    // degree / dinv / CSR build
    hipMemsetAsync(cnt, 0, N_NODES * 4, stream);
    hipMemsetAsync(cursor, 0, N_NODES * 4, stream);
    k_deg<<<(N_EDGES + 255) / 256, 256, 0, stream>>>(dst, cnt);
    k_dinv<<<(N_NODES + 255) / 256, 256, 0, stream>>>(cnt, dinv);
    k_scan1<<<SCAN_BLOCKS, 512, 0, stream>>>(cnt, lofs, bsum);
    k_scan2<<<1, 64, 0, stream>>>(bsum, SCAN_BLOCKS);
    k_scan3<<<(N_NODES + 255) / 256, 256, 0, stream>>>(lofs, bsum, offs);
    k_fill<<<(N_EDGES + 255) / 256, 256, 0, stream>>>(src, dst, offs, cursor, csr_src);

    const int gemm_grid   = (N_NODES + 63) / 64;
    const int gather_grid = (N_NODES + 3) / 4;
    const int apply_grid  = (N_NODES * 32 + 255) / 256;

    struct Layer { const float* in; float* out; const float* W; const float* b;
                   const float* gm; const float* bt; const float* res; };
    Layer layers[3] = {
        { x,    bufA, W1, b1, g1, be1, nullptr },
        { bufA, bufB, W2, b2, g2, be2, bufA    },
        { bufB, bufA, W3, b3, g3, be3, bufB    },
    };

    for (int l = 0; l < 3; ++l) {
        const Layer& L = layers[l];
        k_gemm<<<gemm_grid, 256, 0, stream>>>(L.in, L.W, H);
        k_gather<<<gather_grid, 256, 0, stream>>>(csr_src, offs, dinv, H, L.b, AGG);
        hipMemsetAsync(stats, 0, 2 * CH * 4, stream);
        k_bn_stats<<<1024, 128, 0, stream>>>(AGG, stats);
        k_bn_finalize<<<1, 128, 0, stream>>>(stats, L.gm, L.bt);
        k_bn_apply<<<apply_grid, 256, 0, stream>>>(AGG, stats, L.res, L.out);
    }

    // pooling (layer-3 output is in bufA)
    hipMemsetAsync(psum, 0, (size_t)N_GRAPHS * CH * 4, stream);
    hipMemsetAsync(pmax, 0, (size_t)N_GRAPHS * CH * 4, stream);
    hipMemsetAsync(pcnt, 0, (size_t)N_GRAPHS * 4, stream);
    k_pool<<<apply_grid, 256, 0, stream>>>(bufA, batch, psum, pmax, pcnt);
    k_head<<<N_GRAPHS, 64, 0, stream>>>(psum, pmax, pcnt, Wh, bh, (float*)d_out);
}

// Round 3
// 1033.693 us; speedup vs baseline: 17.2022x; 1.4221x over previous
//
#include <hip/hip_runtime.h>
#include <hip/hip_bf16.h>

#define N_NODES   100000
#define N_EDGES   1600000
#define CH        128
#define N_GRAPHS  512
#define N_CLASSES 64
#define BN_EPS    1e-5f

typedef unsigned int uint;
typedef unsigned short ushort_t;

__device__ __forceinline__ ushort_t f2bf(float f) {
    uint u = __float_as_uint(f);
    uint r = (u + 0x7fffu + ((u >> 16) & 1u)) >> 16;   // round-to-nearest-even
    return (ushort_t)r;
}
__device__ __forceinline__ float bf2f(ushort_t u) {
    return __uint_as_float(((uint)u) << 16);
}

// ---------------- degree count (int) ----------------
__global__ __launch_bounds__(256) void k_deg(const int* __restrict__ dst, int* __restrict__ cnt) {
    int e = blockIdx.x * 256 + threadIdx.x;
    if (e < N_EDGES) atomicAdd(&cnt[dst[e]], 1);
}

__global__ __launch_bounds__(256) void k_dinv(const int* __restrict__ cnt, float* __restrict__ dinv) {
    int i = blockIdx.x * 256 + threadIdx.x;
    if (i < N_NODES) dinv[i] = rsqrtf((float)cnt[i] + 1.0f);
}

// ---------------- exclusive scan (3-kernel, 100K elems) ----------------
__global__ __launch_bounds__(512) void k_scan1(const int* __restrict__ cnt,
                                               int* __restrict__ lofs,
                                               int* __restrict__ bsum) {
    __shared__ int sd[512];
    int t = threadIdx.x;
    int i = blockIdx.x * 512 + t;
    int v = (i < N_NODES) ? cnt[i] : 0;
    sd[t] = v;
    __syncthreads();
    for (int o = 1; o < 512; o <<= 1) {
        int x = (t >= o) ? sd[t - o] : 0;
        __syncthreads();
        sd[t] += x;
        __syncthreads();
    }
    if (i < N_NODES) lofs[i] = sd[t] - v;     // exclusive
    if (t == 511) bsum[blockIdx.x] = sd[511];
}

__global__ __launch_bounds__(64) void k_scan2(int* __restrict__ bsum, int nblocks) {
    if (threadIdx.x == 0 && blockIdx.x == 0) {
        int run = 0;
        for (int b = 0; b < nblocks; ++b) {
            int v = bsum[b];
            bsum[b] = run;
            run += v;
        }
    }
}

__global__ __launch_bounds__(256) void k_scan3(const int* __restrict__ lofs,
                                               const int* __restrict__ bsum,
                                               int* __restrict__ offs) {
    int i = blockIdx.x * 256 + threadIdx.x;
    if (i < N_NODES) offs[i] = lofs[i] + bsum[i >> 9];
    if (i == 0) offs[N_NODES] = N_EDGES;
}

// ---------------- CSR fill ----------------
__global__ __launch_bounds__(256) void k_fill(const int* __restrict__ src,
                                              const int* __restrict__ dst,
                                              const int* __restrict__ offs,
                                              int* __restrict__ cursor,
                                              int* __restrict__ csr_src) {
    int e = blockIdx.x * 256 + threadIdx.x;
    if (e >= N_EDGES) return;
    int d = dst[e];
    int pos = offs[d] + atomicAdd(&cursor[d], 1);
    csr_src[pos] = src[e];
}

// ---------------- GEMM: H(bf16) = X(fp32) @ W(fp32) ----------------
__global__ __launch_bounds__(256) void k_gemm(const float* __restrict__ X,
                                              const float* __restrict__ W,
                                              ushort_t* __restrict__ H) {
    __shared__ float sW[64 * 128];   // [k][c] chunk
    __shared__ float sX[64 * 64];    // [r][k] chunk
    const int t = threadIdx.x;
    const int row0 = blockIdx.x * 64;
    const int cg = t & 31;
    const int rg = t >> 5;

    float acc[8][4];
#pragma unroll
    for (int j = 0; j < 8; ++j) { acc[j][0]=0.f; acc[j][1]=0.f; acc[j][2]=0.f; acc[j][3]=0.f; }

    for (int kc = 0; kc < 128; kc += 64) {
        for (int i = t; i < 2048; i += 256) {
            int off = i * 4;
            int kk = off >> 7;
            int cc = off & 127;
            *(float4*)&sW[off] = *(const float4*)&W[(kc + kk) * 128 + cc];
        }
        for (int i = t; i < 1024; i += 256) {
            int off = i * 4;
            int r = off >> 6;
            int kk = off & 63;
            float4 v = make_float4(0.f, 0.f, 0.f, 0.f);
            int gr = row0 + r;
            if (gr < N_NODES) v = *(const float4*)&X[gr * 128 + kc + kk];
            *(float4*)&sX[off] = v;
        }
        __syncthreads();

        for (int k = 0; k < 64; ++k) {
            float4 w = *(float4*)&sW[k * 128 + cg * 4];
#pragma unroll
            for (int j = 0; j < 8; ++j) {
                float xv = sX[(rg * 8 + j) * 64 + k];
                acc[j][0] += xv * w.x;
                acc[j][1] += xv * w.y;
                acc[j][2] += xv * w.z;
                acc[j][3] += xv * w.w;
            }
        }
        __syncthreads();
    }

#pragma unroll
    for (int j = 0; j < 8; ++j) {
        int r = row0 + rg * 8 + j;
        if (r < N_NODES) {
            ushort4 o;
            o.x = f2bf(acc[j][0]); o.y = f2bf(acc[j][1]);
            o.z = f2bf(acc[j][2]); o.w = f2bf(acc[j][3]);
            *(ushort4*)(H + r * 128 + cg * 4) = o;
        }
    }
}

// ---------------- gather-aggregate: one wave per dst node ----------------
__global__ __launch_bounds__(256) void k_gather(const int* __restrict__ csr_src,
                                                const int* __restrict__ offs,
                                                const float* __restrict__ dinv,
                                                const ushort_t* __restrict__ H,
                                                const float* __restrict__ b,
                                                float* __restrict__ AGG) {
    int node = blockIdx.x * 4 + (threadIdx.x >> 6);
    if (node >= N_NODES) return;
    int lane = threadIdx.x & 63;
    int c = lane * 2;

    float di = dinv[node];
    float d2 = di * di;
    uint hv = *(const uint*)(H + (size_t)node * 128 + c);
    float acc0 = bf2f((ushort_t)(hv & 0xffff)) * d2 + b[c];
    float acc1 = bf2f((ushort_t)(hv >> 16))    * d2 + b[c + 1];

    int beg = offs[node];
    int end = offs[node + 1];
    int s_next = (beg < end) ? csr_src[beg] : 0;
    for (int p = beg; p < end; ++p) {
        int s = s_next;
        if (p + 1 < end) s_next = csr_src[p + 1];
        float coef = dinv[s] * di;
        uint h = *(const uint*)(H + (size_t)s * 128 + c);
        acc0 += coef * bf2f((ushort_t)(h & 0xffff));
        acc1 += coef * bf2f((ushort_t)(h >> 16));
    }

    *(float2*)(AGG + (size_t)node * 128 + c) = make_float2(acc0, acc1);
}

// ---------------- BN stats: per-channel sum / sumsq ----------------
__global__ __launch_bounds__(128) void k_bn_stats(const float* __restrict__ AGG,
                                                  float* __restrict__ stats) {
    int c = threadIdx.x;
    float s = 0.f, q = 0.f;
    for (int i = blockIdx.x; i < N_NODES; i += gridDim.x) {
        float v = AGG[i * 128 + c];
        s += v;
        q += v * v;
    }
    atomicAdd(&stats[c], s);
    atomicAdd(&stats[128 + c], q);
}

__global__ __launch_bounds__(128) void k_bn_finalize(float* __restrict__ stats,
                                                     const float* __restrict__ gamma,
                                                     const float* __restrict__ beta) {
    int c = threadIdx.x;
    const float invN = 1.0f / (float)N_NODES;
    float mu = stats[c] * invN;
    float var = stats[128 + c] * invN - mu * mu;
    float sc = gamma[c] * rsqrtf(var + BN_EPS);
    stats[256 + c] = sc;
    stats[384 + c] = beta[c] - mu * sc;
}

// ---------------- BN apply + ReLU (+ residual) ----------------
__global__ __launch_bounds__(256) void k_bn_apply(const float* __restrict__ AGG,
                                                  const float* __restrict__ stats,
                                                  const float* __restrict__ RES,  // may be null
                                                  float* __restrict__ OUT) {
    int tid = blockIdx.x * 256 + threadIdx.x;
    if (tid >= N_NODES * 32) return;
    int i = tid >> 5;
    int c = (tid & 31) * 4;
    float4 v = *(const float4*)&AGG[i * 128 + c];
    float4 sc = *(const float4*)&stats[256 + c];
    float4 sh = *(const float4*)&stats[384 + c];
    float4 y;
    y.x = v.x * sc.x + sh.x;
    y.y = v.y * sc.y + sh.y;
    y.z = v.z * sc.z + sh.z;
    y.w = v.w * sc.w + sh.w;
    if (RES) {
        float4 r = *(const float4*)&RES[i * 128 + c];
        y.x += r.x; y.y += r.y; y.z += r.z; y.w += r.w;
    }
    y.x = fmaxf(y.x, 0.f); y.y = fmaxf(y.y, 0.f);
    y.z = fmaxf(y.z, 0.f); y.w = fmaxf(y.w, 0.f);
    *(float4*)&OUT[i * 128 + c] = y;
}

// ---------------- pooling: segmented reduction over sorted batch ----------------
// one 128-thread block per chunk of nodes; thread = channel; flush atomics only
// at graph-id boundaries. post-ReLU X >= 0 so uint atomicMax == float max, init 0.
#define POOL_CHUNK 100
__global__ __launch_bounds__(128) void k_pool(const float* __restrict__ X,
                                              const int* __restrict__ batch,
                                              float* __restrict__ psum,
                                              uint* __restrict__ pmax,
                                              float* __restrict__ pcnt) {
    int t = threadIdx.x;                        // channel
    int i0 = blockIdx.x * POOL_CHUNK;
    int i1 = min(i0 + POOL_CHUNK, N_NODES);
    if (i0 >= i1) return;

    int cur = batch[i0];
    float s = 0.f, m = 0.f, cntf = 0.f;
    for (int i = i0; i < i1; ++i) {
        int b = batch[i];                       // broadcast (same addr all lanes)
        float v = X[(size_t)i * 128 + t];
        if (b != cur) {
            atomicAdd(&psum[cur * 128 + t], s);
            atomicMax(&pmax[cur * 128 + t], __float_as_uint(m));
            if (t == 0) atomicAdd(&pcnt[cur], cntf);
            s = 0.f; m = 0.f; cntf = 0.f;
            cur = b;
        }
        s += v;
        m = fmaxf(m, v);
        cntf += 1.f;
    }
    atomicAdd(&psum[cur * 128 + t], s);
    atomicMax(&pmax[cur * 128 + t], __float_as_uint(m));
    if (t == 0) atomicAdd(&pcnt[cur], cntf);
}

// ---------------- head ----------------
__global__ __launch_bounds__(64) void k_head(const float* __restrict__ psum,
                                             const uint* __restrict__ pmax,
                                             const float* __restrict__ pcnt,
                                             const float* __restrict__ Wh,
                                             const float* __restrict__ bh,
                                             float* __restrict__ out) {
    int g = blockIdx.x;
    int o = threadIdx.x;
    float cnt = pcnt[g];
    float inv = 1.0f / fmaxf(cnt, 1.0f);
    float acc = bh[o];
    for (int c = 0; c < 128; ++c) {
        float s = psum[g * 128 + c];
        float m = __uint_as_float(pmax[g * 128 + c]);
        acc += (s * inv) * Wh[c * 64 + o];
        acc += s * Wh[(128 + c) * 64 + o];
        acc += m * Wh[(256 + c) * 64 + o];
    }
    out[g * 64 + o] = acc;
}

// ---------------- host orchestration ----------------
extern "C" void kernel_launch(void* const* d_in, const int* in_sizes, int n_in,
                              void* d_out, int out_size, void* d_ws, size_t ws_size,
                              hipStream_t stream) {
    const float* x     = (const float*)d_in[0];
    const int*   ei    = (const int*)d_in[1];
    const int*   batch = (const int*)d_in[2];
    const float* W1 = (const float*)d_in[3];
    const float* b1 = (const float*)d_in[4];
    const float* g1 = (const float*)d_in[5];
    const float* be1= (const float*)d_in[6];
    const float* W2 = (const float*)d_in[7];
    const float* b2 = (const float*)d_in[8];
    const float* g2 = (const float*)d_in[9];
    const float* be2= (const float*)d_in[10];
    const float* W3 = (const float*)d_in[11];
    const float* b3 = (const float*)d_in[12];
    const float* g3 = (const float*)d_in[13];
    const float* be3= (const float*)d_in[14];
    const float* Wh = (const float*)d_in[15];
    const float* bh = (const float*)d_in[16];

    const int* src = ei;
    const int* dst = ei + N_EDGES;

    char* ws = (char*)d_ws;
    size_t off = 0;
    float* dinv   = (float*)(ws + off);   off += 512 * 1024;
    float* bufA   = (float*)(ws + off);   off += (size_t)N_NODES * CH * 4;
    float* bufB   = (float*)(ws + off);   off += (size_t)N_NODES * CH * 4;
    ushort_t* H   = (ushort_t*)(ws + off);off += (size_t)N_NODES * CH * 2;
    float* AGG    = (float*)(ws + off);   off += (size_t)N_NODES * CH * 4;
    float* stats  = (float*)(ws + off);   off += 512 * 4;
    float* psum   = (float*)(ws + off);   off += (size_t)N_GRAPHS * CH * 4;
    uint*  pmax   = (uint*)(ws + off);    off += (size_t)N_GRAPHS * CH * 4;
    float* pcnt   = (float*)(ws + off);   off += 4096;
    int*   cnt    = (int*)(ws + off);     off += 512 * 1024;
    int*   lofs   = (int*)(ws + off);     off += 512 * 1024;
    int*   offs   = (int*)(ws + off);     off += 512 * 1024;      // N+1 ints
    int*   bsum   = (int*)(ws + off);     off += 4096;
    int*   cursor = (int*)(ws + off);     off += 512 * 1024;
    int*   csr_src= (int*)(ws + off);     off += (size_t)N_EDGES * 4;

    const int SCAN_BLOCKS = (N_NODES + 511) / 512;   // 196

    // degree / dinv / CSR build
    hipMemsetAsync(cnt, 0, N_NODES * 4, stream);
    hipMemsetAsync(cursor, 0, N_NODES * 4, stream);
    k_deg<<<(N_EDGES + 255) / 256, 256, 0, stream>>>(dst, cnt);
    k_dinv<<<(N_NODES + 255) / 256, 256, 0, stream>>>(cnt, dinv);
    k_scan1<<<SCAN_BLOCKS, 512, 0, stream>>>(cnt, lofs, bsum);
    k_scan2<<<1, 64, 0, stream>>>(bsum, SCAN_BLOCKS);
    k_scan3<<<(N_NODES + 255) / 256, 256, 0, stream>>>(lofs, bsum, offs);
    k_fill<<<(N_EDGES + 255) / 256, 256, 0, stream>>>(src, dst, offs, cursor, csr_src);

    const int gemm_grid   = (N_NODES + 63) / 64;
    const int gather_grid = (N_NODES + 3) / 4;
    const int apply_grid  = (N_NODES * 32 + 255) / 256;
    const int pool_grid   = (N_NODES + POOL_CHUNK - 1) / POOL_CHUNK;

    struct Layer { const float* in; float* out; const float* W; const float* b;
                   const float* gm; const float* bt; const float* res; };
    Layer layers[3] = {
        { x,    bufA, W1, b1, g1, be1, nullptr },
        { bufA, bufB, W2, b2, g2, be2, bufA    },
        { bufB, bufA, W3, b3, g3, be3, bufB    },
    };

    for (int l = 0; l < 3; ++l) {
        const Layer& L = layers[l];
        k_gemm<<<gemm_grid, 256, 0, stream>>>(L.in, L.W, H);
        k_gather<<<gather_grid, 256, 0, stream>>>(csr_src, offs, dinv, H, L.b, AGG);
        hipMemsetAsync(stats, 0, 2 * CH * 4, stream);
        k_bn_stats<<<1024, 128, 0, stream>>>(AGG, stats);
        k_bn_finalize<<<1, 128, 0, stream>>>(stats, L.gm, L.bt);
        k_bn_apply<<<apply_grid, 256, 0, stream>>>(AGG, stats, L.res, L.out);
    }

    // pooling (layer-3 output is in bufA)
    hipMemsetAsync(psum, 0, (size_t)N_GRAPHS * CH * 4, stream);
    hipMemsetAsync(pmax, 0, (size_t)N_GRAPHS * CH * 4, stream);
    hipMemsetAsync(pcnt, 0, (size_t)N_GRAPHS * 4, stream);
    k_pool<<<pool_grid, 128, 0, stream>>>(bufA, batch, psum, pmax, pcnt);
    k_head<<<N_GRAPHS, 64, 0, stream>>>(psum, pmax, pcnt, Wh, bh, (float*)d_out);
}

// Round 4
// 860.084 us; speedup vs baseline: 20.6744x; 1.2019x over previous
//
#include <hip/hip_runtime.h>
#include <hip/hip_bf16.h>

#define N_NODES   100000
#define N_EDGES   1600000
#define CH        128
#define N_GRAPHS  512
#define N_CLASSES 64
#define BN_EPS    1e-5f
#define N_PAD     100128   /* N_NODES rounded up past 128-row gemm tile */

typedef unsigned int uint;
typedef unsigned short ushort_t;

typedef short bf16x8 __attribute__((ext_vector_type(8)));
typedef float f32x4  __attribute__((ext_vector_type(4)));

__device__ __forceinline__ ushort_t f2bf(float f) {
    uint u = __float_as_uint(f);
    uint r = (u + 0x7fffu + ((u >> 16) & 1u)) >> 16;   // round-to-nearest-even
    return (ushort_t)r;
}
__device__ __forceinline__ float bf2f(ushort_t u) {
    return __uint_as_float(((uint)u) << 16);
}

// ---------------- degree count (int) ----------------
__global__ __launch_bounds__(256) void k_deg(const int* __restrict__ dst, int* __restrict__ cnt) {
    int e = blockIdx.x * 256 + threadIdx.x;
    if (e < N_EDGES) atomicAdd(&cnt[dst[e]], 1);
}

__global__ __launch_bounds__(256) void k_dinv(const int* __restrict__ cnt, float* __restrict__ dinv) {
    int i = blockIdx.x * 256 + threadIdx.x;
    if (i < N_NODES) dinv[i] = rsqrtf((float)cnt[i] + 1.0f);
}

// ---------------- exclusive scan (3-kernel, 100K elems) ----------------
__global__ __launch_bounds__(512) void k_scan1(const int* __restrict__ cnt,
                                               int* __restrict__ lofs,
                                               int* __restrict__ bsum) {
    __shared__ int sd[512];
    int t = threadIdx.x;
    int i = blockIdx.x * 512 + t;
    int v = (i < N_NODES) ? cnt[i] : 0;
    sd[t] = v;
    __syncthreads();
    for (int o = 1; o < 512; o <<= 1) {
        int x = (t >= o) ? sd[t - o] : 0;
        __syncthreads();
        sd[t] += x;
        __syncthreads();
    }
    if (i < N_NODES) lofs[i] = sd[t] - v;     // exclusive
    if (t == 511) bsum[blockIdx.x] = sd[511];
}

__global__ __launch_bounds__(64) void k_scan2(int* __restrict__ bsum, int nblocks) {
    if (threadIdx.x == 0 && blockIdx.x == 0) {
        int run = 0;
        for (int b = 0; b < nblocks; ++b) {
            int v = bsum[b];
            bsum[b] = run;
            run += v;
        }
    }
}

__global__ __launch_bounds__(256) void k_scan3(const int* __restrict__ lofs,
                                               const int* __restrict__ bsum,
                                               int* __restrict__ offs) {
    int i = blockIdx.x * 256 + threadIdx.x;
    if (i < N_NODES) offs[i] = lofs[i] + bsum[i >> 9];
    if (i == 0) offs[N_NODES] = N_EDGES;
}

// ---------------- CSR fill ----------------
__global__ __launch_bounds__(256) void k_fill(const int* __restrict__ src,
                                              const int* __restrict__ dst,
                                              const int* __restrict__ offs,
                                              int* __restrict__ cursor,
                                              int* __restrict__ csr_src) {
    int e = blockIdx.x * 256 + threadIdx.x;
    if (e >= N_EDGES) return;
    int d = dst[e];
    int pos = offs[d] + atomicAdd(&cursor[d], 1);
    csr_src[pos] = src[e];
}

// ---------------- weight prep: Wt[l][n*128+k] = bf16(W_l[k*128+n]) ----------------
__global__ __launch_bounds__(256) void k_prep(const float* __restrict__ W1,
                                              const float* __restrict__ W2,
                                              const float* __restrict__ W3,
                                              ushort_t* __restrict__ Wt) {
    int tid = blockIdx.x * 256 + threadIdx.x;
    if (tid >= 3 * 16384) return;
    int l = tid >> 14;
    int e = tid & 16383;
    int n = e >> 7;
    int k = e & 127;
    const float* W = (l == 0) ? W1 : (l == 1) ? W2 : W3;
    Wt[l * 16384 + n * 128 + k] = f2bf(W[k * 128 + n]);
}

// ---------------- cast x fp32 -> bf16 ----------------
__global__ __launch_bounds__(256) void k_cast(const float* __restrict__ x,
                                              ushort_t* __restrict__ XB) {
    int tid = blockIdx.x * 256 + threadIdx.x;
    if (tid >= N_NODES * 32) return;
    int i = tid >> 5;
    int c = (tid & 31) * 4;
    float4 v = *(const float4*)&x[(size_t)i * 128 + c];
    ushort4 o;
    o.x = f2bf(v.x); o.y = f2bf(v.y); o.z = f2bf(v.z); o.w = f2bf(v.w);
    *(ushort4*)&XB[(size_t)i * 128 + c] = o;
}

// ---------------- MFMA GEMM: Hs(bf16) = dinv * (XB(bf16) @ W) ----------------
// block = 4 waves; block tile 128x128; wave tile 64x64 (4x4 of 16x16x32 MFMA).
// LDS-free: A rows read direct (pad rows make OOB reads safe; stores guarded),
// B (Wt, [n][k] bf16) read per-wave from L2.
__global__ __launch_bounds__(256) void k_gemm(const ushort_t* __restrict__ XB,
                                              const ushort_t* __restrict__ Wt,
                                              const float* __restrict__ dinv,
                                              ushort_t* __restrict__ H) {
    const int t = threadIdx.x;
    const int wave = t >> 6;
    const int lane = t & 63;
    const int q = lane >> 4;       // quad 0..3
    const int r = lane & 15;
    const int row0 = blockIdx.x * 128 + (wave >> 1) * 64;
    const int col0 = (wave & 1) * 64;

    f32x4 acc[4][4];
#pragma unroll
    for (int i = 0; i < 4; ++i)
#pragma unroll
        for (int j = 0; j < 4; ++j)
            acc[i][j] = (f32x4){0.f, 0.f, 0.f, 0.f};

#pragma unroll
    for (int ks = 0; ks < 4; ++ks) {
        const int k0 = ks * 32 + q * 8;
        bf16x8 a[4], b[4];
#pragma unroll
        for (int i = 0; i < 4; ++i)
            a[i] = *(const bf16x8*)(XB + (size_t)(row0 + i * 16 + r) * 128 + k0);
#pragma unroll
        for (int j = 0; j < 4; ++j)
            b[j] = *(const bf16x8*)(Wt + (size_t)(col0 + j * 16 + r) * 128 + k0);
#pragma unroll
        for (int i = 0; i < 4; ++i)
#pragma unroll
            for (int j = 0; j < 4; ++j)
                acc[i][j] = __builtin_amdgcn_mfma_f32_16x16x32_bf16(a[i], b[j], acc[i][j], 0, 0, 0);
    }

    // D[row=q*4+reg][col=lane&15] per 16x16 tile (verified mapping)
#pragma unroll
    for (int i = 0; i < 4; ++i) {
#pragma unroll
        for (int rg = 0; rg < 4; ++rg) {
            int rr = row0 + i * 16 + q * 4 + rg;
            if (rr < N_NODES) {
                float dv = dinv[rr];
#pragma unroll
                for (int j = 0; j < 4; ++j)
                    H[(size_t)rr * 128 + col0 + j * 16 + r] = f2bf(acc[i][j][rg] * dv);
            }
        }
    }
}

// ---------------- gather-aggregate: one wave per dst node ----------------
// H is pre-scaled by dinv[src]; AGG = dinv[i]*(sum_nbr Hs + Hs[i]) + b
__global__ __launch_bounds__(256) void k_gather(const int* __restrict__ csr_src,
                                                const int* __restrict__ offs,
                                                const float* __restrict__ dinv,
                                                const ushort_t* __restrict__ H,
                                                const float* __restrict__ b,
                                                float* __restrict__ AGG) {
    int node = blockIdx.x * 4 + (threadIdx.x >> 6);
    if (node >= N_NODES) return;
    int lane = threadIdx.x & 63;
    int c = lane * 2;

    uint hv = *(const uint*)(H + (size_t)node * 128 + c);  // self (dinv-scaled)
    float acc0 = bf2f((ushort_t)(hv & 0xffff));
    float acc1 = bf2f((ushort_t)(hv >> 16));

    int p = offs[node];
    int end = offs[node + 1];
    for (; p + 8 <= end; p += 8) {
        int s0 = csr_src[p];     int s1 = csr_src[p + 1];
        int s2 = csr_src[p + 2]; int s3 = csr_src[p + 3];
        int s4 = csr_src[p + 4]; int s5 = csr_src[p + 5];
        int s6 = csr_src[p + 6]; int s7 = csr_src[p + 7];
        uint h0 = *(const uint*)(H + (size_t)s0 * 128 + c);
        uint h1 = *(const uint*)(H + (size_t)s1 * 128 + c);
        uint h2 = *(const uint*)(H + (size_t)s2 * 128 + c);
        uint h3 = *(const uint*)(H + (size_t)s3 * 128 + c);
        uint h4 = *(const uint*)(H + (size_t)s4 * 128 + c);
        uint h5 = *(const uint*)(H + (size_t)s5 * 128 + c);
        uint h6 = *(const uint*)(H + (size_t)s6 * 128 + c);
        uint h7 = *(const uint*)(H + (size_t)s7 * 128 + c);
        acc0 += bf2f((ushort_t)(h0 & 0xffff)) + bf2f((ushort_t)(h1 & 0xffff))
              + bf2f((ushort_t)(h2 & 0xffff)) + bf2f((ushort_t)(h3 & 0xffff))
              + bf2f((ushort_t)(h4 & 0xffff)) + bf2f((ushort_t)(h5 & 0xffff))
              + bf2f((ushort_t)(h6 & 0xffff)) + bf2f((ushort_t)(h7 & 0xffff));
        acc1 += bf2f((ushort_t)(h0 >> 16)) + bf2f((ushort_t)(h1 >> 16))
              + bf2f((ushort_t)(h2 >> 16)) + bf2f((ushort_t)(h3 >> 16))
              + bf2f((ushort_t)(h4 >> 16)) + bf2f((ushort_t)(h5 >> 16))
              + bf2f((ushort_t)(h6 >> 16)) + bf2f((ushort_t)(h7 >> 16));
    }
    for (; p < end; ++p) {
        int s = csr_src[p];
        uint h = *(const uint*)(H + (size_t)s * 128 + c);
        acc0 += bf2f((ushort_t)(h & 0xffff));
        acc1 += bf2f((ushort_t)(h >> 16));
    }

    float di = dinv[node];
    acc0 = acc0 * di + b[c];
    acc1 = acc1 * di + b[c + 1];
    *(float2*)(AGG + (size_t)node * 128 + c) = make_float2(acc0, acc1);
}

// ---------------- BN stats: per-channel sum / sumsq ----------------
__global__ __launch_bounds__(128) void k_bn_stats(const float* __restrict__ AGG,
                                                  float* __restrict__ stats) {
    int c = threadIdx.x;
    float s = 0.f, q = 0.f;
    for (int i = blockIdx.x; i < N_NODES; i += gridDim.x) {
        float v = AGG[(size_t)i * 128 + c];
        s += v;
        q += v * v;
    }
    atomicAdd(&stats[c], s);
    atomicAdd(&stats[128 + c], q);
}

__global__ __launch_bounds__(128) void k_bn_finalize(float* __restrict__ stats,
                                                     const float* __restrict__ gamma,
                                                     const float* __restrict__ beta) {
    int c = threadIdx.x;
    const float invN = 1.0f / (float)N_NODES;
    float mu = stats[c] * invN;
    float var = stats[128 + c] * invN - mu * mu;
    float sc = gamma[c] * rsqrtf(var + BN_EPS);
    stats[256 + c] = sc;
    stats[384 + c] = beta[c] - mu * sc;
}

// ---------------- BN apply + ReLU (+ bf16 residual), bf16 out ----------------
__global__ __launch_bounds__(256) void k_bn_apply(const float* __restrict__ AGG,
                                                  const float* __restrict__ stats,
                                                  const ushort_t* __restrict__ RES,  // may be null
                                                  ushort_t* __restrict__ OUT) {
    int tid = blockIdx.x * 256 + threadIdx.x;
    if (tid >= N_NODES * 32) return;
    int i = tid >> 5;
    int c = (tid & 31) * 4;
    float4 v = *(const float4*)&AGG[(size_t)i * 128 + c];
    float4 sc = *(const float4*)&stats[256 + c];
    float4 sh = *(const float4*)&stats[384 + c];
    float4 y;
    y.x = v.x * sc.x + sh.x;
    y.y = v.y * sc.y + sh.y;
    y.z = v.z * sc.z + sh.z;
    y.w = v.w * sc.w + sh.w;
    if (RES) {
        ushort4 rv = *(const ushort4*)&RES[(size_t)i * 128 + c];
        y.x += bf2f(rv.x); y.y += bf2f(rv.y); y.z += bf2f(rv.z); y.w += bf2f(rv.w);
    }
    ushort4 o;
    o.x = f2bf(fmaxf(y.x, 0.f)); o.y = f2bf(fmaxf(y.y, 0.f));
    o.z = f2bf(fmaxf(y.z, 0.f)); o.w = f2bf(fmaxf(y.w, 0.f));
    *(ushort4*)&OUT[(size_t)i * 128 + c] = o;
}

// ---------------- pooling: segmented reduction over sorted batch (bf16 in) ----------------
#define POOL_CHUNK 100
__global__ __launch_bounds__(128) void k_pool(const ushort_t* __restrict__ X,
                                              const int* __restrict__ batch,
                                              float* __restrict__ psum,
                                              uint* __restrict__ pmax,
                                              float* __restrict__ pcnt) {
    int t = threadIdx.x;                        // channel
    int i0 = blockIdx.x * POOL_CHUNK;
    int i1 = min(i0 + POOL_CHUNK, N_NODES);
    if (i0 >= i1) return;

    int cur = batch[i0];
    float s = 0.f, m = 0.f, cntf = 0.f;
    for (int i = i0; i < i1; ++i) {
        int b = batch[i];
        float v = bf2f(X[(size_t)i * 128 + t]);
        if (b != cur) {
            atomicAdd(&psum[cur * 128 + t], s);
            atomicMax(&pmax[cur * 128 + t], __float_as_uint(m));
            if (t == 0) atomicAdd(&pcnt[cur], cntf);
            s = 0.f; m = 0.f; cntf = 0.f;
            cur = b;
        }
        s += v;
        m = fmaxf(m, v);
        cntf += 1.f;
    }
    atomicAdd(&psum[cur * 128 + t], s);
    atomicMax(&pmax[cur * 128 + t], __float_as_uint(m));
    if (t == 0) atomicAdd(&pcnt[cur], cntf);
}

// ---------------- head ----------------
__global__ __launch_bounds__(64) void k_head(const float* __restrict__ psum,
                                             const uint* __restrict__ pmax,
                                             const float* __restrict__ pcnt,
                                             const float* __restrict__ Wh,
                                             const float* __restrict__ bh,
                                             float* __restrict__ out) {
    int g = blockIdx.x;
    int o = threadIdx.x;
    float cnt = pcnt[g];
    float inv = 1.0f / fmaxf(cnt, 1.0f);
    float acc = bh[o];
    for (int c = 0; c < 128; ++c) {
        float s = psum[g * 128 + c];
        float m = __uint_as_float(pmax[g * 128 + c]);
        acc += (s * inv) * Wh[c * 64 + o];
        acc += s * Wh[(128 + c) * 64 + o];
        acc += m * Wh[(256 + c) * 64 + o];
    }
    out[g * 64 + o] = acc;
}

// ---------------- host orchestration ----------------
extern "C" void kernel_launch(void* const* d_in, const int* in_sizes, int n_in,
                              void* d_out, int out_size, void* d_ws, size_t ws_size,
                              hipStream_t stream) {
    const float* x     = (const float*)d_in[0];
    const int*   ei    = (const int*)d_in[1];
    const int*   batch = (const int*)d_in[2];
    const float* W1 = (const float*)d_in[3];
    const float* b1 = (const float*)d_in[4];
    const float* g1 = (const float*)d_in[5];
    const float* be1= (const float*)d_in[6];
    const float* W2 = (const float*)d_in[7];
    const float* b2 = (const float*)d_in[8];
    const float* g2 = (const float*)d_in[9];
    const float* be2= (const float*)d_in[10];
    const float* W3 = (const float*)d_in[11];
    const float* b3 = (const float*)d_in[12];
    const float* g3 = (const float*)d_in[13];
    const float* be3= (const float*)d_in[14];
    const float* Wh = (const float*)d_in[15];
    const float* bh = (const float*)d_in[16];

    const int* src = ei;
    const int* dst = ei + N_EDGES;

    char* ws = (char*)d_ws;
    size_t off = 0;
    float* dinv    = (float*)(ws + off);    off += 512 * 1024;
    ushort_t* XBA  = (ushort_t*)(ws + off); off += (size_t)N_PAD * CH * 2;
    ushort_t* XBB  = (ushort_t*)(ws + off); off += (size_t)N_PAD * CH * 2;
    ushort_t* H    = (ushort_t*)(ws + off); off += (size_t)N_PAD * CH * 2;
    float* AGG     = (float*)(ws + off);    off += (size_t)N_NODES * CH * 4;
    ushort_t* Wt   = (ushort_t*)(ws + off); off += 3 * 16384 * 2;
    float* stats   = (float*)(ws + off);    off += 512 * 4;
    float* psum    = (float*)(ws + off);    off += (size_t)N_GRAPHS * CH * 4;
    uint*  pmax    = (uint*)(ws + off);     off += (size_t)N_GRAPHS * CH * 4;
    float* pcnt    = (float*)(ws + off);    off += 4096;
    int*   cnt     = (int*)(ws + off);      off += 512 * 1024;
    int*   lofs    = (int*)(ws + off);      off += 512 * 1024;
    int*   offs    = (int*)(ws + off);      off += 512 * 1024;      // N+1 ints
    int*   bsum    = (int*)(ws + off);      off += 4096;
    int*   cursor  = (int*)(ws + off);      off += 512 * 1024;
    int*   csr_src = (int*)(ws + off);      off += (size_t)N_EDGES * 4;

    const int SCAN_BLOCKS = (N_NODES + 511) / 512;   // 196

    // weight transpose + x cast
    k_prep<<<(3 * 16384 + 255) / 256, 256, 0, stream>>>(W1, W2, W3, Wt);
    k_cast<<<(N_NODES * 32 + 255) / 256, 256, 0, stream>>>(x, XBA);

    // degree / dinv / CSR build
    hipMemsetAsync(cnt, 0, N_NODES * 4, stream);
    hipMemsetAsync(cursor, 0, N_NODES * 4, stream);
    k_deg<<<(N_EDGES + 255) / 256, 256, 0, stream>>>(dst, cnt);
    k_dinv<<<(N_NODES + 255) / 256, 256, 0, stream>>>(cnt, dinv);
    k_scan1<<<SCAN_BLOCKS, 512, 0, stream>>>(cnt, lofs, bsum);
    k_scan2<<<1, 64, 0, stream>>>(bsum, SCAN_BLOCKS);
    k_scan3<<<(N_NODES + 255) / 256, 256, 0, stream>>>(lofs, bsum, offs);
    k_fill<<<(N_EDGES + 255) / 256, 256, 0, stream>>>(src, dst, offs, cursor, csr_src);

    const int gemm_grid   = (N_NODES + 127) / 128;   // 782
    const int gather_grid = (N_NODES + 3) / 4;
    const int apply_grid  = (N_NODES * 32 + 255) / 256;
    const int pool_grid   = (N_NODES + POOL_CHUNK - 1) / POOL_CHUNK;

    struct Layer { const ushort_t* in; ushort_t* out; const ushort_t* Wt; const float* b;
                   const float* gm; const float* bt; const ushort_t* res; };
    Layer layers[3] = {
        { XBA, XBB, Wt,             b1, g1, be1, nullptr },
        { XBB, XBA, Wt + 16384,     b2, g2, be2, XBB     },
        { XBA, XBB, Wt + 2 * 16384, b3, g3, be3, XBA     },
    };

    for (int l = 0; l < 3; ++l) {
        const Layer& L = layers[l];
        k_gemm<<<gemm_grid, 256, 0, stream>>>(L.in, L.Wt, dinv, H);
        k_gather<<<gather_grid, 256, 0, stream>>>(csr_src, offs, dinv, H, L.b, AGG);
        hipMemsetAsync(stats, 0, 2 * CH * 4, stream);
        k_bn_stats<<<1024, 128, 0, stream>>>(AGG, stats);
        k_bn_finalize<<<1, 128, 0, stream>>>(stats, L.gm, L.bt);
        k_bn_apply<<<apply_grid, 256, 0, stream>>>(AGG, stats, L.res, L.out);
    }

    // pooling (layer-3 output is in XBB)
    hipMemsetAsync(psum, 0, (size_t)N_GRAPHS * CH * 4, stream);
    hipMemsetAsync(pmax, 0, (size_t)N_GRAPHS * CH * 4, stream);
    hipMemsetAsync(pcnt, 0, (size_t)N_GRAPHS * 4, stream);
    k_pool<<<pool_grid, 128, 0, stream>>>(XBB, batch, psum, pmax, pcnt);
    k_head<<<N_GRAPHS, 64, 0, stream>>>(psum, pmax, pcnt, Wh, bh, (float*)d_out);
}

// Round 5
// 787.743 us; speedup vs baseline: 22.5730x; 1.0918x over previous
//
#include <hip/hip_runtime.h>
#include <hip/hip_bf16.h>

#define N_NODES   100000
#define N_EDGES   1600000
#define CH        128
#define N_GRAPHS  512
#define N_CLASSES 64
#define BN_EPS    1e-5f
#define N_PAD     100128   /* N_NODES rounded up past 128-row gemm tile */

typedef unsigned int uint;
typedef unsigned short ushort_t;

typedef short bf16x8 __attribute__((ext_vector_type(8)));
typedef float f32x4  __attribute__((ext_vector_type(4)));

__device__ __forceinline__ ushort_t f2bf(float f) {
    uint u = __float_as_uint(f);
    uint r = (u + 0x7fffu + ((u >> 16) & 1u)) >> 16;   // round-to-nearest-even
    return (ushort_t)r;
}
__device__ __forceinline__ float bf2f(ushort_t u) {
    return __uint_as_float(((uint)u) << 16);
}

// ---------------- degree count + per-edge rank ----------------
__global__ __launch_bounds__(256) void k_deg(const int* __restrict__ dst,
                                             int* __restrict__ cnt,
                                             int* __restrict__ rank) {
    int e = blockIdx.x * 256 + threadIdx.x;
    if (e < N_EDGES) rank[e] = atomicAdd(&cnt[dst[e]], 1);
}

// ---------------- exclusive scan (3-kernel, 100K elems) ----------------
__global__ __launch_bounds__(512) void k_scan1(const int* __restrict__ cnt,
                                               int* __restrict__ lofs,
                                               int* __restrict__ bsum) {
    __shared__ int sd[512];
    int t = threadIdx.x;
    int i = blockIdx.x * 512 + t;
    int v = (i < N_NODES) ? cnt[i] : 0;
    sd[t] = v;
    __syncthreads();
    for (int o = 1; o < 512; o <<= 1) {
        int x = (t >= o) ? sd[t - o] : 0;
        __syncthreads();
        sd[t] += x;
        __syncthreads();
    }
    if (i < N_NODES) lofs[i] = sd[t] - v;     // exclusive
    if (t == 511) bsum[blockIdx.x] = sd[511];
}

// parallel LDS scan of block sums (196 <= 256)
__global__ __launch_bounds__(256) void k_scan2(int* __restrict__ bsum, int nblocks) {
    __shared__ int sd[256];
    int t = threadIdx.x;
    int v = (t < nblocks) ? bsum[t] : 0;
    sd[t] = v;
    __syncthreads();
    for (int o = 1; o < 256; o <<= 1) {
        int x = (t >= o) ? sd[t - o] : 0;
        __syncthreads();
        sd[t] += x;
        __syncthreads();
    }
    if (t < nblocks) bsum[t] = sd[t] - v;     // exclusive
}

// final offsets + dinv (fused)
__global__ __launch_bounds__(256) void k_scan3(const int* __restrict__ lofs,
                                               const int* __restrict__ bsum,
                                               const int* __restrict__ cnt,
                                               int* __restrict__ offs,
                                               float* __restrict__ dinv) {
    int i = blockIdx.x * 256 + threadIdx.x;
    if (i < N_NODES) {
        offs[i] = lofs[i] + bsum[i >> 9];
        dinv[i] = rsqrtf((float)cnt[i] + 1.0f);
    }
    if (i == 0) offs[N_NODES] = N_EDGES;
}

// ---------------- CSR fill (no atomics: rank precomputed) ----------------
__global__ __launch_bounds__(256) void k_fill(const int* __restrict__ src,
                                              const int* __restrict__ dst,
                                              const int* __restrict__ offs,
                                              const int* __restrict__ rank,
                                              int* __restrict__ csr_src) {
    int e = blockIdx.x * 256 + threadIdx.x;
    if (e >= N_EDGES) return;
    int pos = offs[dst[e]] + rank[e];
    csr_src[pos] = src[e];
}

// ---------------- weight prep: Wt[l][n*128+k] = bf16(W_l[k*128+n]) ----------------
__global__ __launch_bounds__(256) void k_prep(const float* __restrict__ W1,
                                              const float* __restrict__ W2,
                                              const float* __restrict__ W3,
                                              ushort_t* __restrict__ Wt) {
    int tid = blockIdx.x * 256 + threadIdx.x;
    if (tid >= 3 * 16384) return;
    int l = tid >> 14;
    int e = tid & 16383;
    int n = e >> 7;
    int k = e & 127;
    const float* W = (l == 0) ? W1 : (l == 1) ? W2 : W3;
    Wt[l * 16384 + n * 128 + k] = f2bf(W[k * 128 + n]);
}

// ---------------- cast x fp32 -> bf16 ----------------
__global__ __launch_bounds__(256) void k_cast(const float* __restrict__ x,
                                              ushort_t* __restrict__ XB) {
    int tid = blockIdx.x * 256 + threadIdx.x;
    if (tid >= N_NODES * 32) return;
    int i = tid >> 5;
    int c = (tid & 31) * 4;
    float4 v = *(const float4*)&x[(size_t)i * 128 + c];
    ushort4 o;
    o.x = f2bf(v.x); o.y = f2bf(v.y); o.z = f2bf(v.z); o.w = f2bf(v.w);
    *(ushort4*)&XB[(size_t)i * 128 + c] = o;
}

// ---------------- MFMA GEMM: Hs(bf16) = dinv * (XB(bf16) @ W) ----------------
__global__ __launch_bounds__(256) void k_gemm(const ushort_t* __restrict__ XB,
                                              const ushort_t* __restrict__ Wt,
                                              const float* __restrict__ dinv,
                                              ushort_t* __restrict__ H) {
    const int t = threadIdx.x;
    const int wave = t >> 6;
    const int lane = t & 63;
    const int q = lane >> 4;       // quad 0..3
    const int r = lane & 15;
    const int row0 = blockIdx.x * 128 + (wave >> 1) * 64;
    const int col0 = (wave & 1) * 64;

    f32x4 acc[4][4];
#pragma unroll
    for (int i = 0; i < 4; ++i)
#pragma unroll
        for (int j = 0; j < 4; ++j)
            acc[i][j] = (f32x4){0.f, 0.f, 0.f, 0.f};

#pragma unroll
    for (int ks = 0; ks < 4; ++ks) {
        const int k0 = ks * 32 + q * 8;
        bf16x8 a[4], b[4];
#pragma unroll
        for (int i = 0; i < 4; ++i)
            a[i] = *(const bf16x8*)(XB + (size_t)(row0 + i * 16 + r) * 128 + k0);
#pragma unroll
        for (int j = 0; j < 4; ++j)
            b[j] = *(const bf16x8*)(Wt + (size_t)(col0 + j * 16 + r) * 128 + k0);
#pragma unroll
        for (int i = 0; i < 4; ++i)
#pragma unroll
            for (int j = 0; j < 4; ++j)
                acc[i][j] = __builtin_amdgcn_mfma_f32_16x16x32_bf16(a[i], b[j], acc[i][j], 0, 0, 0);
    }

#pragma unroll
    for (int i = 0; i < 4; ++i) {
#pragma unroll
        for (int rg = 0; rg < 4; ++rg) {
            int rr = row0 + i * 16 + q * 4 + rg;
            if (rr < N_NODES) {
                float dv = dinv[rr];
#pragma unroll
                for (int j = 0; j < 4; ++j)
                    H[(size_t)rr * 128 + col0 + j * 16 + r] = f2bf(acc[i][j][rg] * dv);
            }
        }
    }
}

// ---------------- gather-aggregate: one wave per dst node ----------------
__global__ __launch_bounds__(256) void k_gather(const int* __restrict__ csr_src,
                                                const int* __restrict__ offs,
                                                const float* __restrict__ dinv,
                                                const ushort_t* __restrict__ H,
                                                const float* __restrict__ b,
                                                float* __restrict__ AGG) {
    int node = blockIdx.x * 4 + (threadIdx.x >> 6);
    if (node >= N_NODES) return;
    int lane = threadIdx.x & 63;
    int c = lane * 2;

    uint hv = *(const uint*)(H + (size_t)node * 128 + c);  // self (dinv-scaled)
    float acc0 = bf2f((ushort_t)(hv & 0xffff));
    float acc1 = bf2f((ushort_t)(hv >> 16));

    int p = offs[node];
    int end = offs[node + 1];
    for (; p + 8 <= end; p += 8) {
        int s0 = csr_src[p];     int s1 = csr_src[p + 1];
        int s2 = csr_src[p + 2]; int s3 = csr_src[p + 3];
        int s4 = csr_src[p + 4]; int s5 = csr_src[p + 5];
        int s6 = csr_src[p + 6]; int s7 = csr_src[p + 7];
        uint h0 = *(const uint*)(H + (size_t)s0 * 128 + c);
        uint h1 = *(const uint*)(H + (size_t)s1 * 128 + c);
        uint h2 = *(const uint*)(H + (size_t)s2 * 128 + c);
        uint h3 = *(const uint*)(H + (size_t)s3 * 128 + c);
        uint h4 = *(const uint*)(H + (size_t)s4 * 128 + c);
        uint h5 = *(const uint*)(H + (size_t)s5 * 128 + c);
        uint h6 = *(const uint*)(H + (size_t)s6 * 128 + c);
        uint h7 = *(const uint*)(H + (size_t)s7 * 128 + c);
        acc0 += bf2f((ushort_t)(h0 & 0xffff)) + bf2f((ushort_t)(h1 & 0xffff))
              + bf2f((ushort_t)(h2 & 0xffff)) + bf2f((ushort_t)(h3 & 0xffff))
              + bf2f((ushort_t)(h4 & 0xffff)) + bf2f((ushort_t)(h5 & 0xffff))
              + bf2f((ushort_t)(h6 & 0xffff)) + bf2f((ushort_t)(h7 & 0xffff));
        acc1 += bf2f((ushort_t)(h0 >> 16)) + bf2f((ushort_t)(h1 >> 16))
              + bf2f((ushort_t)(h2 >> 16)) + bf2f((ushort_t)(h3 >> 16))
              + bf2f((ushort_t)(h4 >> 16)) + bf2f((ushort_t)(h5 >> 16))
              + bf2f((ushort_t)(h6 >> 16)) + bf2f((ushort_t)(h7 >> 16));
    }
    for (; p < end; ++p) {
        int s = csr_src[p];
        uint h = *(const uint*)(H + (size_t)s * 128 + c);
        acc0 += bf2f((ushort_t)(h & 0xffff));
        acc1 += bf2f((ushort_t)(h >> 16));
    }

    float di = dinv[node];
    acc0 = acc0 * di + b[c];
    acc1 = acc1 * di + b[c + 1];
    *(float2*)(AGG + (size_t)node * 128 + c) = make_float2(acc0, acc1);
}

// ---------------- BN stats: per-channel sum / sumsq ----------------
__global__ __launch_bounds__(128) void k_bn_stats(const float* __restrict__ AGG,
                                                  float* __restrict__ stats) {
    int c = threadIdx.x;
    float s = 0.f, q = 0.f;
    for (int i = blockIdx.x; i < N_NODES; i += gridDim.x) {
        float v = AGG[(size_t)i * 128 + c];
        s += v;
        q += v * v;
    }
    atomicAdd(&stats[c], s);
    atomicAdd(&stats[128 + c], q);
}

__global__ __launch_bounds__(128) void k_bn_finalize(float* __restrict__ stats,
                                                     const float* __restrict__ gamma,
                                                     const float* __restrict__ beta) {
    int c = threadIdx.x;
    const float invN = 1.0f / (float)N_NODES;
    float mu = stats[c] * invN;
    float var = stats[128 + c] * invN - mu * mu;
    float sc = gamma[c] * rsqrtf(var + BN_EPS);
    stats[256 + c] = sc;
    stats[384 + c] = beta[c] - mu * sc;
}

// ---------------- BN apply + ReLU (+ bf16 residual), bf16 out ----------------
__global__ __launch_bounds__(256) void k_bn_apply(const float* __restrict__ AGG,
                                                  const float* __restrict__ stats,
                                                  const ushort_t* __restrict__ RES,  // may be null
                                                  ushort_t* __restrict__ OUT) {
    int tid = blockIdx.x * 256 + threadIdx.x;
    if (tid >= N_NODES * 32) return;
    int i = tid >> 5;
    int c = (tid & 31) * 4;
    float4 v = *(const float4*)&AGG[(size_t)i * 128 + c];
    float4 sc = *(const float4*)&stats[256 + c];
    float4 sh = *(const float4*)&stats[384 + c];
    float4 y;
    y.x = v.x * sc.x + sh.x;
    y.y = v.y * sc.y + sh.y;
    y.z = v.z * sc.z + sh.z;
    y.w = v.w * sc.w + sh.w;
    if (RES) {
        ushort4 rv = *(const ushort4*)&RES[(size_t)i * 128 + c];
        y.x += bf2f(rv.x); y.y += bf2f(rv.y); y.z += bf2f(rv.z); y.w += bf2f(rv.w);
    }
    ushort4 o;
    o.x = f2bf(fmaxf(y.x, 0.f)); o.y = f2bf(fmaxf(y.y, 0.f));
    o.z = f2bf(fmaxf(y.z, 0.f)); o.w = f2bf(fmaxf(y.w, 0.f));
    *(ushort4*)&OUT[(size_t)i * 128 + c] = o;
}

// ---------------- pooling: segmented reduction over sorted batch (bf16 in) ----------------
#define POOL_CHUNK 100
__global__ __launch_bounds__(128) void k_pool(const ushort_t* __restrict__ X,
                                              const int* __restrict__ batch,
                                              float* __restrict__ psum,
                                              uint* __restrict__ pmax,
                                              float* __restrict__ pcnt) {
    int t = threadIdx.x;                        // channel
    int i0 = blockIdx.x * POOL_CHUNK;
    int i1 = min(i0 + POOL_CHUNK, N_NODES);
    if (i0 >= i1) return;

    int cur = batch[i0];
    float s = 0.f, m = 0.f, cntf = 0.f;
    for (int i = i0; i < i1; ++i) {
        int b = batch[i];
        float v = bf2f(X[(size_t)i * 128 + t]);
        if (b != cur) {
            atomicAdd(&psum[cur * 128 + t], s);
            atomicMax(&pmax[cur * 128 + t], __float_as_uint(m));
            if (t == 0) atomicAdd(&pcnt[cur], cntf);
            s = 0.f; m = 0.f; cntf = 0.f;
            cur = b;
        }
        s += v;
        m = fmaxf(m, v);
        cntf += 1.f;
    }
    atomicAdd(&psum[cur * 128 + t], s);
    atomicMax(&pmax[cur * 128 + t], __float_as_uint(m));
    if (t == 0) atomicAdd(&pcnt[cur], cntf);
}

// ---------------- head ----------------
__global__ __launch_bounds__(64) void k_head(const float* __restrict__ psum,
                                             const uint* __restrict__ pmax,
                                             const float* __restrict__ pcnt,
                                             const float* __restrict__ Wh,
                                             const float* __restrict__ bh,
                                             float* __restrict__ out) {
    int g = blockIdx.x;
    int o = threadIdx.x;
    float cnt = pcnt[g];
    float inv = 1.0f / fmaxf(cnt, 1.0f);
    float acc = bh[o];
    for (int c = 0; c < 128; ++c) {
        float s = psum[g * 128 + c];
        float m = __uint_as_float(pmax[g * 128 + c]);
        acc += (s * inv) * Wh[c * 64 + o];
        acc += s * Wh[(128 + c) * 64 + o];
        acc += m * Wh[(256 + c) * 64 + o];
    }
    out[g * 64 + o] = acc;
}

// ---------------- host orchestration ----------------
extern "C" void kernel_launch(void* const* d_in, const int* in_sizes, int n_in,
                              void* d_out, int out_size, void* d_ws, size_t ws_size,
                              hipStream_t stream) {
    const float* x     = (const float*)d_in[0];
    const int*   ei    = (const int*)d_in[1];
    const int*   batch = (const int*)d_in[2];
    const float* W1 = (const float*)d_in[3];
    const float* b1 = (const float*)d_in[4];
    const float* g1 = (const float*)d_in[5];
    const float* be1= (const float*)d_in[6];
    const float* W2 = (const float*)d_in[7];
    const float* b2 = (const float*)d_in[8];
    const float* g2 = (const float*)d_in[9];
    const float* be2= (const float*)d_in[10];
    const float* W3 = (const float*)d_in[11];
    const float* b3 = (const float*)d_in[12];
    const float* g3 = (const float*)d_in[13];
    const float* be3= (const float*)d_in[14];
    const float* Wh = (const float*)d_in[15];
    const float* bh = (const float*)d_in[16];

    const int* src = ei;
    const int* dst = ei + N_EDGES;

    char* ws = (char*)d_ws;
    size_t off = 0;

    // ---- zero-initialized contiguous region (single memset) ----
    char* zero_base = ws;
    int*   cnt     = (int*)(ws + off);      off += 400384;                       // N_NODES*4 padded
    float* stats   = (float*)(ws + off);    off += 3 * 512 * 4;                  // 3 layers x 512 floats
    float* psum    = (float*)(ws + off);    off += (size_t)N_GRAPHS * CH * 4;
    uint*  pmax    = (uint*)(ws + off);     off += (size_t)N_GRAPHS * CH * 4;
    float* pcnt    = (float*)(ws + off);    off += 4096;
    size_t zero_bytes = off;

    // ---- uninitialized scratch ----
    float* dinv    = (float*)(ws + off);    off += 512 * 1024;
    ushort_t* XBA  = (ushort_t*)(ws + off); off += (size_t)N_PAD * CH * 2;
    ushort_t* XBB  = (ushort_t*)(ws + off); off += (size_t)N_PAD * CH * 2;
    ushort_t* H    = (ushort_t*)(ws + off); off += (size_t)N_PAD * CH * 2;
    float* AGG     = (float*)(ws + off);    off += (size_t)N_NODES * CH * 4;
    ushort_t* Wt   = (ushort_t*)(ws + off); off += 3 * 16384 * 2;
    int*   lofs    = (int*)(ws + off);      off += 512 * 1024;
    int*   offs    = (int*)(ws + off);      off += 512 * 1024;      // N+1 ints
    int*   bsum    = (int*)(ws + off);      off += 4096;
    int*   rank    = (int*)(ws + off);      off += (size_t)N_EDGES * 4;
    int*   csr_src = (int*)(ws + off);      off += (size_t)N_EDGES * 4;

    const int SCAN_BLOCKS = (N_NODES + 511) / 512;   // 196

    hipMemsetAsync(zero_base, 0, zero_bytes, stream);

    // weight transpose + x cast
    k_prep<<<(3 * 16384 + 255) / 256, 256, 0, stream>>>(W1, W2, W3, Wt);
    k_cast<<<(N_NODES * 32 + 255) / 256, 256, 0, stream>>>(x, XBA);

    // degree(+rank) / scan(+dinv) / CSR fill
    k_deg<<<(N_EDGES + 255) / 256, 256, 0, stream>>>(dst, cnt, rank);
    k_scan1<<<SCAN_BLOCKS, 512, 0, stream>>>(cnt, lofs, bsum);
    k_scan2<<<1, 256, 0, stream>>>(bsum, SCAN_BLOCKS);
    k_scan3<<<(N_NODES + 255) / 256, 256, 0, stream>>>(lofs, bsum, cnt, offs, dinv);
    k_fill<<<(N_EDGES + 255) / 256, 256, 0, stream>>>(src, dst, offs, rank, csr_src);

    const int gemm_grid   = (N_NODES + 127) / 128;   // 782
    const int gather_grid = (N_NODES + 3) / 4;
    const int apply_grid  = (N_NODES * 32 + 255) / 256;
    const int pool_grid   = (N_NODES + POOL_CHUNK - 1) / POOL_CHUNK;

    struct Layer { const ushort_t* in; ushort_t* out; const ushort_t* Wt; const float* b;
                   const float* gm; const float* bt; const ushort_t* res; };
    Layer layers[3] = {
        { XBA, XBB, Wt,             b1, g1, be1, nullptr },
        { XBB, XBA, Wt + 16384,     b2, g2, be2, XBB     },
        { XBA, XBB, Wt + 2 * 16384, b3, g3, be3, XBA     },
    };

    for (int l = 0; l < 3; ++l) {
        const Layer& L = layers[l];
        float* st = stats + l * 512;
        k_gemm<<<gemm_grid, 256, 0, stream>>>(L.in, L.Wt, dinv, H);
        k_gather<<<gather_grid, 256, 0, stream>>>(csr_src, offs, dinv, H, L.b, AGG);
        k_bn_stats<<<1024, 128, 0, stream>>>(AGG, st);
        k_bn_finalize<<<1, 128, 0, stream>>>(st, L.gm, L.bt);
        k_bn_apply<<<apply_grid, 256, 0, stream>>>(AGG, st, L.res, L.out);
    }

    // pooling (layer-3 output is in XBB)
    k_pool<<<pool_grid, 128, 0, stream>>>(XBB, batch, psum, pmax, pcnt);
    k_head<<<N_GRAPHS, 64, 0, stream>>>(psum, pmax, pcnt, Wh, bh, (float*)d_out);
}

// Round 6
// 735.121 us; speedup vs baseline: 24.1889x; 1.0716x over previous
//
#include <hip/hip_runtime.h>
#include <hip/hip_bf16.h>

#define N_NODES   100000
#define N_EDGES   1600000
#define CH        128
#define N_GRAPHS  512
#define N_CLASSES 64
#define BN_EPS    1e-5f
#define N_PAD     100128   /* N_NODES rounded up past 128-row gemm tile */

typedef unsigned int uint;
typedef unsigned short ushort_t;

typedef short bf16x8 __attribute__((ext_vector_type(8)));
typedef float f32x4  __attribute__((ext_vector_type(4)));

__device__ __forceinline__ ushort_t f2bf(float f) {
    uint u = __float_as_uint(f);
    uint r = (u + 0x7fffu + ((u >> 16) & 1u)) >> 16;   // round-to-nearest-even
    return (ushort_t)r;
}
__device__ __forceinline__ float bf2f(ushort_t u) {
    return __uint_as_float(((uint)u) << 16);
}

// ---------------- degree count + per-edge rank ----------------
__global__ __launch_bounds__(256) void k_deg(const int* __restrict__ dst,
                                             int* __restrict__ cnt,
                                             int* __restrict__ rank) {
    int e = blockIdx.x * 256 + threadIdx.x;
    if (e < N_EDGES) rank[e] = atomicAdd(&cnt[dst[e]], 1);
}

// ---------------- exclusive scan (3-kernel, 100K elems) ----------------
__global__ __launch_bounds__(512) void k_scan1(const int* __restrict__ cnt,
                                               int* __restrict__ lofs,
                                               int* __restrict__ bsum) {
    __shared__ int sd[512];
    int t = threadIdx.x;
    int i = blockIdx.x * 512 + t;
    int v = (i < N_NODES) ? cnt[i] : 0;
    sd[t] = v;
    __syncthreads();
    for (int o = 1; o < 512; o <<= 1) {
        int x = (t >= o) ? sd[t - o] : 0;
        __syncthreads();
        sd[t] += x;
        __syncthreads();
    }
    if (i < N_NODES) lofs[i] = sd[t] - v;     // exclusive
    if (t == 511) bsum[blockIdx.x] = sd[511];
}

// parallel LDS scan of block sums (196 <= 256)
__global__ __launch_bounds__(256) void k_scan2(int* __restrict__ bsum, int nblocks) {
    __shared__ int sd[256];
    int t = threadIdx.x;
    int v = (t < nblocks) ? bsum[t] : 0;
    sd[t] = v;
    __syncthreads();
    for (int o = 1; o < 256; o <<= 1) {
        int x = (t >= o) ? sd[t - o] : 0;
        __syncthreads();
        sd[t] += x;
        __syncthreads();
    }
    if (t < nblocks) bsum[t] = sd[t] - v;     // exclusive
}

// final offsets + dinv (fused)
__global__ __launch_bounds__(256) void k_scan3(const int* __restrict__ lofs,
                                               const int* __restrict__ bsum,
                                               const int* __restrict__ cnt,
                                               int* __restrict__ offs,
                                               float* __restrict__ dinv) {
    int i = blockIdx.x * 256 + threadIdx.x;
    if (i < N_NODES) {
        offs[i] = lofs[i] + bsum[i >> 9];
        dinv[i] = rsqrtf((float)cnt[i] + 1.0f);
    }
    if (i == 0) offs[N_NODES] = N_EDGES;
}

// ---------------- CSR fill (no atomics: rank precomputed) ----------------
__global__ __launch_bounds__(256) void k_fill(const int* __restrict__ src,
                                              const int* __restrict__ dst,
                                              const int* __restrict__ offs,
                                              const int* __restrict__ rank,
                                              int* __restrict__ csr_src) {
    int e = blockIdx.x * 256 + threadIdx.x;
    if (e >= N_EDGES) return;
    int pos = offs[dst[e]] + rank[e];
    csr_src[pos] = src[e];
}

// ---------------- fused weight transpose + x cast ----------------
// blocks [0,192): Wt[l][n*128+k] = bf16(W_l[k*128+n]);  blocks [192,...): x -> bf16
#define PREP_BLOCKS 192
__global__ __launch_bounds__(256) void k_precast(const float* __restrict__ W1,
                                                 const float* __restrict__ W2,
                                                 const float* __restrict__ W3,
                                                 ushort_t* __restrict__ Wt,
                                                 const float* __restrict__ x,
                                                 ushort_t* __restrict__ XB) {
    if (blockIdx.x < PREP_BLOCKS) {
        int tid = blockIdx.x * 256 + threadIdx.x;      // < 3*16384
        int l = tid >> 14;
        int e = tid & 16383;
        int n = e >> 7;
        int k = e & 127;
        const float* W = (l == 0) ? W1 : (l == 1) ? W2 : W3;
        Wt[l * 16384 + n * 128 + k] = f2bf(W[k * 128 + n]);
    } else {
        int tid = (blockIdx.x - PREP_BLOCKS) * 256 + threadIdx.x;
        if (tid >= N_NODES * 32) return;
        int i = tid >> 5;
        int c = (tid & 31) * 4;
        float4 v = *(const float4*)&x[(size_t)i * 128 + c];
        ushort4 o;
        o.x = f2bf(v.x); o.y = f2bf(v.y); o.z = f2bf(v.z); o.w = f2bf(v.w);
        *(ushort4*)&XB[(size_t)i * 128 + c] = o;
    }
}

// ---------------- MFMA GEMM: Hs(bf16) = dinv * (XB(bf16) @ W) ----------------
__global__ __launch_bounds__(256) void k_gemm(const ushort_t* __restrict__ XB,
                                              const ushort_t* __restrict__ Wt,
                                              const float* __restrict__ dinv,
                                              ushort_t* __restrict__ H) {
    const int t = threadIdx.x;
    const int wave = t >> 6;
    const int lane = t & 63;
    const int q = lane >> 4;       // quad 0..3
    const int r = lane & 15;
    const int row0 = blockIdx.x * 128 + (wave >> 1) * 64;
    const int col0 = (wave & 1) * 64;

    f32x4 acc[4][4];
#pragma unroll
    for (int i = 0; i < 4; ++i)
#pragma unroll
        for (int j = 0; j < 4; ++j)
            acc[i][j] = (f32x4){0.f, 0.f, 0.f, 0.f};

#pragma unroll
    for (int ks = 0; ks < 4; ++ks) {
        const int k0 = ks * 32 + q * 8;
        bf16x8 a[4], b[4];
#pragma unroll
        for (int i = 0; i < 4; ++i)
            a[i] = *(const bf16x8*)(XB + (size_t)(row0 + i * 16 + r) * 128 + k0);
#pragma unroll
        for (int j = 0; j < 4; ++j)
            b[j] = *(const bf16x8*)(Wt + (size_t)(col0 + j * 16 + r) * 128 + k0);
#pragma unroll
        for (int i = 0; i < 4; ++i)
#pragma unroll
            for (int j = 0; j < 4; ++j)
                acc[i][j] = __builtin_amdgcn_mfma_f32_16x16x32_bf16(a[i], b[j], acc[i][j], 0, 0, 0);
    }

#pragma unroll
    for (int i = 0; i < 4; ++i) {
#pragma unroll
        for (int rg = 0; rg < 4; ++rg) {
            int rr = row0 + i * 16 + q * 4 + rg;
            if (rr < N_NODES) {
                float dv = dinv[rr];
#pragma unroll
                for (int j = 0; j < 4; ++j)
                    H[(size_t)rr * 128 + col0 + j * 16 + r] = f2bf(acc[i][j][rg] * dv);
            }
        }
    }
}

// ---------------- gather-aggregate v2: one wave per dst node, 2 edges per pass ----------------
// lanes 0..31 = edge A (4 ch each via uint2), lanes 32..63 = edge B; butterfly combine.
// AGG (bf16) = dinv[i]*(sum_nbr Hs + Hs[i]) + b
__global__ __launch_bounds__(256) void k_gather(const int* __restrict__ csr_src,
                                                const int* __restrict__ offs,
                                                const float* __restrict__ dinv,
                                                const ushort_t* __restrict__ H,
                                                const float* __restrict__ b,
                                                ushort_t* __restrict__ AGG) {
    int node = blockIdx.x * 4 + (threadIdx.x >> 6);
    if (node >= N_NODES) return;
    int lane = threadIdx.x & 63;
    int pair = lane >> 5;          // which edge of the dual
    int cl = lane & 31;
    int c = cl * 4;                // 4 channels per lane

    float a0 = 0.f, a1 = 0.f, a2 = 0.f, a3 = 0.f;
    if (pair == 0) {               // self term (dinv-scaled H row)
        uint2 hv = *(const uint2*)(H + (size_t)node * 128 + c);
        a0 = bf2f((ushort_t)(hv.x & 0xffff)); a1 = bf2f((ushort_t)(hv.x >> 16));
        a2 = bf2f((ushort_t)(hv.y & 0xffff)); a3 = bf2f((ushort_t)(hv.y >> 16));
    }

    int p = offs[node];
    int end = offs[node + 1];

#define ACCUM(hv)  do { \
        a0 += bf2f((ushort_t)((hv).x & 0xffff)); a1 += bf2f((ushort_t)((hv).x >> 16)); \
        a2 += bf2f((ushort_t)((hv).y & 0xffff)); a3 += bf2f((ushort_t)((hv).y >> 16)); } while (0)

    for (; p + 16 <= end; p += 16) {          // 16 edges: 8 dual-loads in flight
        int s0 = csr_src[p      + pair], s1 = csr_src[p +  2 + pair];
        int s2 = csr_src[p +  4 + pair], s3 = csr_src[p +  6 + pair];
        int s4 = csr_src[p +  8 + pair], s5 = csr_src[p + 10 + pair];
        int s6 = csr_src[p + 12 + pair], s7 = csr_src[p + 14 + pair];
        uint2 h0 = *(const uint2*)(H + (size_t)s0 * 128 + c);
        uint2 h1 = *(const uint2*)(H + (size_t)s1 * 128 + c);
        uint2 h2 = *(const uint2*)(H + (size_t)s2 * 128 + c);
        uint2 h3 = *(const uint2*)(H + (size_t)s3 * 128 + c);
        uint2 h4 = *(const uint2*)(H + (size_t)s4 * 128 + c);
        uint2 h5 = *(const uint2*)(H + (size_t)s5 * 128 + c);
        uint2 h6 = *(const uint2*)(H + (size_t)s6 * 128 + c);
        uint2 h7 = *(const uint2*)(H + (size_t)s7 * 128 + c);
        ACCUM(h0); ACCUM(h1); ACCUM(h2); ACCUM(h3);
        ACCUM(h4); ACCUM(h5); ACCUM(h6); ACCUM(h7);
    }
    for (; p + 4 <= end; p += 4) {            // 4 edges: 2 dual-loads
        int s0 = csr_src[p + pair], s1 = csr_src[p + 2 + pair];
        uint2 h0 = *(const uint2*)(H + (size_t)s0 * 128 + c);
        uint2 h1 = *(const uint2*)(H + (size_t)s1 * 128 + c);
        ACCUM(h0); ACCUM(h1);
    }
    for (; p < end; p += 2) {                 // tail: 1-2 edges, predicated
        int idx = p + pair;
        bool ok = idx < end;
        int s = csr_src[ok ? idx : p];
        uint2 h = *(const uint2*)(H + (size_t)s * 128 + c);
        if (ok) ACCUM(h);
    }
#undef ACCUM

    a0 += __shfl_xor(a0, 32);
    a1 += __shfl_xor(a1, 32);
    a2 += __shfl_xor(a2, 32);
    a3 += __shfl_xor(a3, 32);

    if (pair == 0) {
        float di = dinv[node];
        a0 = a0 * di + b[c];     a1 = a1 * di + b[c + 1];
        a2 = a2 * di + b[c + 2]; a3 = a3 * di + b[c + 3];
        uint2 o;
        o.x = (uint)f2bf(a0) | ((uint)f2bf(a1) << 16);
        o.y = (uint)f2bf(a2) | ((uint)f2bf(a3) << 16);
        *(uint2*)(AGG + (size_t)node * 128 + c) = o;
    }
}

// ---------------- BN stats: per-channel sum / sumsq (bf16 in) ----------------
__global__ __launch_bounds__(128) void k_bn_stats(const ushort_t* __restrict__ AGG,
                                                  float* __restrict__ stats) {
    int c = threadIdx.x;
    float s = 0.f, q = 0.f;
    for (int i = blockIdx.x; i < N_NODES; i += gridDim.x) {
        float v = bf2f(AGG[(size_t)i * 128 + c]);
        s += v;
        q += v * v;
    }
    atomicAdd(&stats[c], s);
    atomicAdd(&stats[128 + c], q);
}

// ---------------- BN apply (finalize fused) + ReLU (+ bf16 residual), bf16 out ----------------
__global__ __launch_bounds__(256) void k_bn_apply(const ushort_t* __restrict__ AGG,
                                                  const float* __restrict__ stats,
                                                  const float* __restrict__ gamma,
                                                  const float* __restrict__ beta,
                                                  const ushort_t* __restrict__ RES,  // may be null
                                                  ushort_t* __restrict__ OUT) {
    int tid = blockIdx.x * 256 + threadIdx.x;
    if (tid >= N_NODES * 32) return;
    int i = tid >> 5;
    int c = (tid & 31) * 4;

    const float invN = 1.0f / (float)N_NODES;
    float4 sm = *(const float4*)&stats[c];
    float4 sq = *(const float4*)&stats[128 + c];
    float4 gm = *(const float4*)&gamma[c];
    float4 bt = *(const float4*)&beta[c];
    float mu0 = sm.x * invN, mu1 = sm.y * invN, mu2 = sm.z * invN, mu3 = sm.w * invN;
    float sc0 = gm.x * rsqrtf(sq.x * invN - mu0 * mu0 + BN_EPS);
    float sc1 = gm.y * rsqrtf(sq.y * invN - mu1 * mu1 + BN_EPS);
    float sc2 = gm.z * rsqrtf(sq.z * invN - mu2 * mu2 + BN_EPS);
    float sc3 = gm.w * rsqrtf(sq.w * invN - mu3 * mu3 + BN_EPS);
    float sh0 = bt.x - mu0 * sc0, sh1 = bt.y - mu1 * sc1;
    float sh2 = bt.z - mu2 * sc2, sh3 = bt.w - mu3 * sc3;

    uint2 av = *(const uint2*)&AGG[(size_t)i * 128 + c];
    float y0 = bf2f((ushort_t)(av.x & 0xffff)) * sc0 + sh0;
    float y1 = bf2f((ushort_t)(av.x >> 16))    * sc1 + sh1;
    float y2 = bf2f((ushort_t)(av.y & 0xffff)) * sc2 + sh2;
    float y3 = bf2f((ushort_t)(av.y >> 16))    * sc3 + sh3;
    if (RES) {
        ushort4 rv = *(const ushort4*)&RES[(size_t)i * 128 + c];
        y0 += bf2f(rv.x); y1 += bf2f(rv.y); y2 += bf2f(rv.z); y3 += bf2f(rv.w);
    }
    ushort4 o;
    o.x = f2bf(fmaxf(y0, 0.f)); o.y = f2bf(fmaxf(y1, 0.f));
    o.z = f2bf(fmaxf(y2, 0.f)); o.w = f2bf(fmaxf(y3, 0.f));
    *(ushort4*)&OUT[(size_t)i * 128 + c] = o;
}

// ---------------- pooling: segmented reduction over sorted batch (bf16 in) ----------------
#define POOL_CHUNK 100
__global__ __launch_bounds__(128) void k_pool(const ushort_t* __restrict__ X,
                                              const int* __restrict__ batch,
                                              float* __restrict__ psum,
                                              uint* __restrict__ pmax,
                                              float* __restrict__ pcnt) {
    int t = threadIdx.x;                        // channel
    int i0 = blockIdx.x * POOL_CHUNK;
    int i1 = min(i0 + POOL_CHUNK, N_NODES);
    if (i0 >= i1) return;

    int cur = batch[i0];
    float s = 0.f, m = 0.f, cntf = 0.f;
    for (int i = i0; i < i1; ++i) {
        int b = batch[i];
        float v = bf2f(X[(size_t)i * 128 + t]);
        if (b != cur) {
            atomicAdd(&psum[cur * 128 + t], s);
            atomicMax(&pmax[cur * 128 + t], __float_as_uint(m));
            if (t == 0) atomicAdd(&pcnt[cur], cntf);
            s = 0.f; m = 0.f; cntf = 0.f;
            cur = b;
        }
        s += v;
        m = fmaxf(m, v);
        cntf += 1.f;
    }
    atomicAdd(&psum[cur * 128 + t], s);
    atomicMax(&pmax[cur * 128 + t], __float_as_uint(m));
    if (t == 0) atomicAdd(&pcnt[cur], cntf);
}

// ---------------- head ----------------
__global__ __launch_bounds__(64) void k_head(const float* __restrict__ psum,
                                             const uint* __restrict__ pmax,
                                             const float* __restrict__ pcnt,
                                             const float* __restrict__ Wh,
                                             const float* __restrict__ bh,
                                             float* __restrict__ out) {
    int g = blockIdx.x;
    int o = threadIdx.x;
    float cnt = pcnt[g];
    float inv = 1.0f / fmaxf(cnt, 1.0f);
    float acc = bh[o];
    for (int c = 0; c < 128; ++c) {
        float s = psum[g * 128 + c];
        float m = __uint_as_float(pmax[g * 128 + c]);
        acc += (s * inv) * Wh[c * 64 + o];
        acc += s * Wh[(128 + c) * 64 + o];
        acc += m * Wh[(256 + c) * 64 + o];
    }
    out[g * 64 + o] = acc;
}

// ---------------- host orchestration ----------------
extern "C" void kernel_launch(void* const* d_in, const int* in_sizes, int n_in,
                              void* d_out, int out_size, void* d_ws, size_t ws_size,
                              hipStream_t stream) {
    const float* x     = (const float*)d_in[0];
    const int*   ei    = (const int*)d_in[1];
    const int*   batch = (const int*)d_in[2];
    const float* W1 = (const float*)d_in[3];
    const float* b1 = (const float*)d_in[4];
    const float* g1 = (const float*)d_in[5];
    const float* be1= (const float*)d_in[6];
    const float* W2 = (const float*)d_in[7];
    const float* b2 = (const float*)d_in[8];
    const float* g2 = (const float*)d_in[9];
    const float* be2= (const float*)d_in[10];
    const float* W3 = (const float*)d_in[11];
    const float* b3 = (const float*)d_in[12];
    const float* g3 = (const float*)d_in[13];
    const float* be3= (const float*)d_in[14];
    const float* Wh = (const float*)d_in[15];
    const float* bh = (const float*)d_in[16];

    const int* src = ei;
    const int* dst = ei + N_EDGES;

    char* ws = (char*)d_ws;
    size_t off = 0;

    // ---- zero-initialized contiguous region (single memset) ----
    char* zero_base = ws;
    int*   cnt     = (int*)(ws + off);      off += 400384;                       // N_NODES*4 padded
    float* stats   = (float*)(ws + off);    off += 3 * 512 * 4;                  // 3 layers x 512 floats
    float* psum    = (float*)(ws + off);    off += (size_t)N_GRAPHS * CH * 4;
    uint*  pmax    = (uint*)(ws + off);     off += (size_t)N_GRAPHS * CH * 4;
    float* pcnt    = (float*)(ws + off);    off += 4096;
    size_t zero_bytes = off;

    // ---- uninitialized scratch ----
    float* dinv    = (float*)(ws + off);    off += 512 * 1024;
    ushort_t* XBA  = (ushort_t*)(ws + off); off += (size_t)N_PAD * CH * 2;
    ushort_t* XBB  = (ushort_t*)(ws + off); off += (size_t)N_PAD * CH * 2;
    ushort_t* H    = (ushort_t*)(ws + off); off += (size_t)N_PAD * CH * 2;
    ushort_t* AGG  = (ushort_t*)(ws + off); off += (size_t)N_NODES * CH * 2;
    ushort_t* Wt   = (ushort_t*)(ws + off); off += 3 * 16384 * 2;
    int*   lofs    = (int*)(ws + off);      off += 512 * 1024;
    int*   offs    = (int*)(ws + off);      off += 512 * 1024;      // N+1 ints
    int*   bsum    = (int*)(ws + off);      off += 4096;
    int*   rank    = (int*)(ws + off);      off += (size_t)N_EDGES * 4;
    int*   csr_src = (int*)(ws + off);      off += (size_t)N_EDGES * 4;

    const int SCAN_BLOCKS = (N_NODES + 511) / 512;   // 196

    hipMemsetAsync(zero_base, 0, zero_bytes, stream);

    // fused weight transpose + x cast
    const int cast_blocks = (N_NODES * 32 + 255) / 256;
    k_precast<<<PREP_BLOCKS + cast_blocks, 256, 0, stream>>>(W1, W2, W3, Wt, x, XBA);

    // degree(+rank) / scan(+dinv) / CSR fill
    k_deg<<<(N_EDGES + 255) / 256, 256, 0, stream>>>(dst, cnt, rank);
    k_scan1<<<SCAN_BLOCKS, 512, 0, stream>>>(cnt, lofs, bsum);
    k_scan2<<<1, 256, 0, stream>>>(bsum, SCAN_BLOCKS);
    k_scan3<<<(N_NODES + 255) / 256, 256, 0, stream>>>(lofs, bsum, cnt, offs, dinv);
    k_fill<<<(N_EDGES + 255) / 256, 256, 0, stream>>>(src, dst, offs, rank, csr_src);

    const int gemm_grid   = (N_NODES + 127) / 128;   // 782
    const int gather_grid = (N_NODES + 3) / 4;
    const int apply_grid  = (N_NODES * 32 + 255) / 256;
    const int pool_grid   = (N_NODES + POOL_CHUNK - 1) / POOL_CHUNK;

    struct Layer { const ushort_t* in; ushort_t* out; const ushort_t* Wt; const float* b;
                   const float* gm; const float* bt; const ushort_t* res; };
    Layer layers[3] = {
        { XBA, XBB, Wt,             b1, g1, be1, nullptr },
        { XBB, XBA, Wt + 16384,     b2, g2, be2, XBB     },
        { XBA, XBB, Wt + 2 * 16384, b3, g3, be3, XBA     },
    };

    for (int l = 0; l < 3; ++l) {
        const Layer& L = layers[l];
        float* st = stats + l * 512;
        k_gemm<<<gemm_grid, 256, 0, stream>>>(L.in, L.Wt, dinv, H);
        k_gather<<<gather_grid, 256, 0, stream>>>(csr_src, offs, dinv, H, L.b, AGG);
        k_bn_stats<<<1024, 128, 0, stream>>>(AGG, st);
        k_bn_apply<<<apply_grid, 256, 0, stream>>>(AGG, st, L.gm, L.bt, L.res, L.out);
    }

    // pooling (layer-3 output is in XBB)
    k_pool<<<pool_grid, 128, 0, stream>>>(XBB, batch, psum, pmax, pcnt);
    k_head<<<N_GRAPHS, 64, 0, stream>>>(psum, pmax, pcnt, Wh, bh, (float*)d_out);
}